// Round 6
// baseline (401.392 us; speedup 1.0000x reference)
//
#include <hip/hip_runtime.h>

// EGNN conv: N=50000, E=800000, C=64.
// Round 13 == round 12 resubmitted (round-5 bench was GPUAcquisitionTimeout, no
// data). Dependency-packed pipeline. K1 = passA hist + frag + zero + copy.
// K2 = sort_fused: scan(63) -> scat(250, spins on scan_done) -> node_pre(782,
// independent filler that hides the sort chain) -> bsort(196, dispatched last,
// spins on scat_done). Same in-order-dispatch + agent-scope acquire/release
// contract the verified lookback scan already uses. LDS unioned (~35KB max ->
// 4 blocks/CU; all waitees within first 1024 resident blocks -> no deadlock).
// Edge/node kernels byte-identical to the 199.6us round-11 build. 4 dispatches.

#define NN 50000
#define NE 800000
#define ETILE 12500         // NE/64

// sort geometry
#define SBLK 250            // passA/scat blocks
#define SCHUNK 3200         // NE/SBLK edges per block
#define NBUK 196            // buckets = ceil(50000/256)
#define GHN 64000           // 256*SBLK counters
#define SCAN_NB 63          // 63 blocks * 256 thr * 4 elems = 64512 >= 64000

typedef __attribute__((ext_vector_type(8))) short bf16x8;
typedef __attribute__((ext_vector_type(4))) short bf16x4;
typedef __attribute__((ext_vector_type(4))) float f32x4;

#define MFMA16(a, b, c) __builtin_amdgcn_mfma_f32_16x16x32_bf16(a, b, c, 0, 0, 0)

__device__ __forceinline__ unsigned short f2b(float x) {
    union { float f; unsigned u; } v; v.f = x;
    return (unsigned short)((v.u + 0x8000u) >> 16);
}
__device__ __forceinline__ float b2f(unsigned short b) {
    union { unsigned u; float f; } v; v.u = ((unsigned)b) << 16; return v.f;
}
__device__ __forceinline__ float silu_f(float x) {
    return x * __builtin_amdgcn_rcpf(1.0f + __expf(-x));
}

// wfrag layout (40 frags x 512 bf16): 0..7 We2, 8..15 Wc1, 16..31 Wn1,
// 32..39 Wn2. node_pre loads We1 directly from global (L2-resident).

// ---------------- K1: passA || frag || zero || copy ----------------

#define P1_A 250
#define P1_FRAG 10
#define P1_ZERO 200
#define P1_COPY 16
#define P1_FRAG0 (P1_A)
#define P1_ZERO0 (P1_FRAG0 + P1_FRAG)
#define P1_COPY0 (P1_ZERO0 + P1_ZERO)
#define K1_GRID (P1_COPY0 + P1_COPY)

__global__ __launch_bounds__(256, 4) void prep_kernel(
    const float* __restrict__ pos,
    const float* __restrict__ We2, const float* __restrict__ Wc1,
    const float* __restrict__ Wn1, const float* __restrict__ Wn2,
    const int* __restrict__ ei,
    unsigned short* __restrict__ wfrag, int* __restrict__ gh,
    float* __restrict__ msg_agg, float* __restrict__ pos_out,
    float4* __restrict__ pos4)
{
    __shared__ int lh[256];
    const int b = blockIdx.x, tid = threadIdx.x;
    if (b < P1_A) {
        // coarse bucket histogram for this block's 3200 edges
        lh[tid] = 0;
        __syncthreads();
        const int base = b * SCHUNK;
        for (int i = base + tid; i < base + SCHUNK; i += 256)
            atomicAdd(&lh[ei[i] >> 8], 1);
        __syncthreads();
        gh[tid * SBLK + b] = lh[tid];   // bucket-major [256][SBLK]
    } else if (b < P1_ZERO0) {
        const int lane = tid & 63, w = tid >> 6;
        const int li = lane & 15, lg = lane >> 4;
        const int f = (b - P1_FRAG0) * 4 + w;  // 0..39
        const float* W; int g;
        if (f < 8)       { W = We2; g = f; }
        else if (f < 16) { W = Wc1; g = f - 8; }
        else if (f < 32) { W = Wn1; g = f - 16; }
        else             { W = Wn2; g = f - 32; }
        const int ks = g >> 2, ni = g & 3;
        const int n = ni * 16 + li, kb = ks * 32 + (lg << 3);
        bf16x8 v;
#pragma unroll
        for (int j = 0; j < 8; ++j) v[j] = (short)f2b(W[(kb + j) * 64 + n]);
        *(bf16x8*)(wfrag + (size_t)f * 512 + lane * 8) = v;
    } else if (b < P1_COPY0) {
        float4* dst = (float4*)msg_agg;
        int i = (b - P1_ZERO0) * 256 + tid;
        for (; i < NN * 16; i += P1_ZERO * 256) dst[i] = make_float4(0.f, 0.f, 0.f, 0.f);
    } else {
        if (b == P1_COPY0 && tid < 128) gh[GHN + tid] = 0;  // scan aux + done ctrs
        int i = (b - P1_COPY0) * 256 + tid;
        for (; i < 37500 + NN; i += P1_COPY * 256) {
            if (i < 37500) {
                ((float4*)pos_out)[i] = ((const float4*)pos)[i];
            } else {
                const int n = i - 37500;
                pos4[n] = make_float4(pos[3 * n], pos[3 * n + 1], pos[3 * n + 2], 0.f);
            }
        }
    }
}

// ---------------- K2: sort_fused = scan | scat | node_pre | bsort ----------------
// aux[0..63) aggregates, aux[63..126) flags, aux[126]=scan_done, aux[127]=scat_done.
// Waiters always dispatched AFTER their waitees (in-order CP dispatch, same
// contract as the verified lookback scan).

#define K2_SCAN 63
#define K2_SCAT0 63
#define K2_NPRE0 313
#define K2_BS0 1095
#define K2_GRID 1291

union K2Smem {
    struct { unsigned short sH[64][72]; unsigned short sT[4][16][72]; } np;
    struct { int wsum[4]; int prefix; } scn;
    struct { int off[256]; } st;
    struct { int2 stage[4096]; int h2[256]; int sc2[256]; int off2[256]; } bs;
};

__global__ __launch_bounds__(256) void sort_fused_kernel(
    const float* __restrict__ h, const float* __restrict__ be1,
    const float* __restrict__ We1, const int* __restrict__ ei,
    int* __restrict__ gh,
    unsigned short* __restrict__ a1r, unsigned short* __restrict__ a1c,
    int2* __restrict__ sorted_rc)
{
    __shared__ __align__(16) K2Smem smem;
    const int b = blockIdx.x, tid = threadIdx.x;
    int* aux = gh + GHN;
    const int lane = tid & 63, wid = tid >> 6;

    if (b < K2_SCAN) {
        // ---- scan over GHN elems, 4 per thread ----
        const int base4 = (b * 256 + tid) * 4;
        int vv[4];
#pragma unroll
        for (int i = 0; i < 4; ++i) {
            const int idx = base4 + i;
            vv[i] = (idx < GHN) ? gh[idx] : 0;
        }
        const int s = vv[0] + vv[1] + vv[2] + vv[3];
        int inc = s;
#pragma unroll
        for (int d = 1; d < 64; d <<= 1) {
            const int o = __shfl_up(inc, d, 64);
            if (lane >= d) inc += o;
        }
        if (lane == 63) smem.scn.wsum[wid] = inc;
        __syncthreads();
        if (tid == 0) {
            int run = 0;
#pragma unroll
            for (int i = 0; i < 4; ++i) {
                const int tmp = smem.scn.wsum[i]; smem.scn.wsum[i] = run; run += tmp;
            }
            __hip_atomic_store(&aux[b], run, __ATOMIC_RELAXED, __HIP_MEMORY_SCOPE_AGENT);
            __hip_atomic_store(&aux[SCAN_NB + b], 1, __ATOMIC_RELEASE, __HIP_MEMORY_SCOPE_AGENT);
        }
        __syncthreads();
        const int thr_excl = smem.scn.wsum[wid] + inc - s;
        if (tid < 64) {
            int s2 = 0;
            if (tid < b) {
                while (__hip_atomic_load(&aux[SCAN_NB + tid], __ATOMIC_ACQUIRE,
                                         __HIP_MEMORY_SCOPE_AGENT) == 0) {
                    __builtin_amdgcn_s_sleep(2);
                }
                s2 = __hip_atomic_load(&aux[tid], __ATOMIC_RELAXED, __HIP_MEMORY_SCOPE_AGENT);
            }
#pragma unroll
            for (int m = 1; m < 64; m <<= 1) s2 += __shfl_xor(s2, m, 64);
            if (tid == 0) smem.scn.prefix = s2;
        }
        __syncthreads();
        int run = smem.scn.prefix + thr_excl;
#pragma unroll
        for (int i = 0; i < 4; ++i) {
            const int idx = base4 + i;
            if (idx < GHN) gh[idx] = run;
            run += vv[i];
        }
        __syncthreads();
        if (tid == 0)
            __hip_atomic_fetch_add(&aux[126], 1, __ATOMIC_RELEASE, __HIP_MEMORY_SCOPE_AGENT);
    } else if (b < K2_NPRE0) {
        // ---- scat: wait for scan, then scatter to coarse-bucket regions ----
        while (__hip_atomic_load(&aux[126], __ATOMIC_ACQUIRE,
                                 __HIP_MEMORY_SCOPE_AGENT) != K2_SCAN) {
            __builtin_amdgcn_s_sleep(2);
        }
        const int bb = b - K2_SCAT0;
        smem.st.off[tid] = gh[tid * SBLK + bb];
        __syncthreads();
        const int base = bb * SCHUNK;
        for (int i = base + tid; i < base + SCHUNK; i += 256) {
            const int r = ei[i];
            const int c = ei[NE + i];
            const int p = atomicAdd(&smem.st.off[r >> 8], 1);
            sorted_rc[p] = make_int2(r, c);
        }
        __syncthreads();
        if (tid == 0)
            __hip_atomic_fetch_add(&aux[127], 1, __ATOMIC_RELEASE, __HIP_MEMORY_SCOPE_AGENT);
    } else if (b < K2_BS0) {
        // ---- node_pre filler: one 64-node tile per block (no dependencies) ----
        const int li = lane & 15, lg = lane >> 4;
        const int w = wid;
        const int t = b - K2_NPRE0;
        const int c4 = lane & 15, rsub = lane >> 4;
#pragma unroll
        for (int pass = 0; pass < 4; ++pass) {
            const int n_loc = w * 16 + pass * 4 + rsub;
            const int n = t * 64 + n_loc;
            float4 hv = make_float4(0.f, 0.f, 0.f, 0.f);
            if (n < NN) hv = *(const float4*)&h[(size_t)n * 64 + c4 * 4];
            bf16x4 hp;
            hp[0] = (short)f2b(hv.x); hp[1] = (short)f2b(hv.y);
            hp[2] = (short)f2b(hv.z); hp[3] = (short)f2b(hv.w);
            *(bf16x4*)&smem.np.sH[n_loc][c4 * 4] = hp;   // wave-private rows
        }
        float be1v[4];
#pragma unroll
        for (int ni = 0; ni < 4; ++ni) be1v[ni] = be1[ni * 16 + li];

#pragma unroll
        for (int half = 0; half < 2; ++half) {
            unsigned short* out = half ? a1c : a1r;
            f32x4 acc[4];
#pragma unroll
            for (int ni = 0; ni < 4; ++ni) acc[ni] = (f32x4)(0.0f);
#pragma unroll
            for (int ks = 0; ks < 2; ++ks) {
                const bf16x8 afr = *(const bf16x8*)&smem.np.sH[w * 16 + li][ks * 32 + (lg << 3)];
#pragma unroll
                for (int ni = 0; ni < 4; ++ni) {
                    const float* Wp = We1 +
                        (size_t)(half * 64 + ks * 32 + (lg << 3)) * 64 + ni * 16 + li;
                    bf16x8 bfr;
#pragma unroll
                    for (int j = 0; j < 8; ++j) bfr[j] = (short)f2b(Wp[(size_t)j * 64]);
                    acc[ni] = MFMA16(afr, bfr, acc[ni]);
                }
            }
#pragma unroll
            for (int ni = 0; ni < 4; ++ni)
#pragma unroll
                for (int reg = 0; reg < 4; ++reg)
                    smem.np.sT[w][lg * 4 + reg][ni * 16 + li] =
                        f2b(acc[ni][reg] + (half ? 0.f : be1v[ni]));
#pragma unroll
            for (int pass = 0; pass < 2; ++pass) {
                const int rr = pass * 8 + (lane >> 3);
                const int n = t * 64 + w * 16 + rr;
                const bf16x8 v = *(const bf16x8*)&smem.np.sT[w][rr][(lane & 7) * 8];
                if (n < NN) *(bf16x8*)&out[(size_t)n * 64 + (lane & 7) * 8] = v;
            }
        }
    } else {
        // ---- bsort: wait for all scat, then per-bucket counting sort ----
        while (__hip_atomic_load(&aux[127], __ATOMIC_ACQUIRE,
                                 __HIP_MEMORY_SCOPE_AGENT) != SBLK) {
            __builtin_amdgcn_s_sleep(2);
        }
        const int k = b - K2_BS0, t = tid;
        const int start = gh[k * SBLK];
        const int end   = gh[(k + 1) * SBLK];
        for (int cb = start; cb < end; cb += 4096) {
            const int cnt = min(4096, end - cb);
            smem.bs.h2[t] = 0;
            __syncthreads();
            int2 le[16];
            int nloc = 0;
#pragma unroll
            for (int jj = 0; jj < 16; ++jj) {
                const int j = jj * 256 + t;
                if (j < cnt) {
                    const int2 e = sorted_rc[cb + j];
                    le[jj] = e;
                    atomicAdd(&smem.bs.h2[e.x & 255], 1);
                    nloc = jj + 1;
                }
            }
            __syncthreads();
            smem.bs.sc2[t] = smem.bs.h2[t];
            __syncthreads();
            for (int d = 1; d < 256; d <<= 1) {
                const int v = (t >= d) ? smem.bs.sc2[t - d] : 0;
                __syncthreads();
                smem.bs.sc2[t] += v;
                __syncthreads();
            }
            smem.bs.off2[t] = smem.bs.sc2[t] - smem.bs.h2[t];   // exclusive prefix
            __syncthreads();
#pragma unroll
            for (int jj = 0; jj < 16; ++jj) {
                if (jj < nloc) {
                    const int rank = atomicAdd(&smem.bs.off2[le[jj].x & 255], 1);
                    smem.bs.stage[rank] = le[jj];
                }
            }
            __syncthreads();
            for (int j = t; j < cnt; j += 256) sorted_rc[cb + j] = smem.bs.stage[j];
            __syncthreads();
        }
    }
}

// ---------------- K3: edge kernel (byte-identical to round 8/11) ----------------

__global__ __launch_bounds__(256, 6) void egnn_edge_kernel(
    const float4* __restrict__ pos4, const int2* __restrict__ sorted_rc,
    const unsigned short* __restrict__ a1r, const unsigned short* __restrict__ a1c,
    const float* __restrict__ We1,  // row 128 = dist weights
    const unsigned short* __restrict__ wfrag,
    const float* __restrict__ be2, const float* __restrict__ bc1,
    const float* __restrict__ Wc2, const float* __restrict__ bc2,
    float* __restrict__ msg_agg, float* __restrict__ pos_out)
{
    __shared__ __align__(16) unsigned short sA[64][80];  // [edge][chan]
    __shared__ __align__(8) int2 srce[64];               // (row,col)
    __shared__ __align__(16) float4 sdr[64];             // (rx,ry,rz,dsq)
    __shared__ float scw[64];

    const int tid = threadIdx.x;
    const int lane = tid & 63, w = tid >> 6;
    const int li = lane & 15, lg = lane >> 4;
    const int tile = blockIdx.x;
    const int e0 = w * 16;

    // phase 0 (per wave, lanes 0-15): endpoints + relpos for own 16 edges
    if (lane < 16) {
        const int e = e0 + lane;
        const int2 rc = sorted_rc[tile * 64 + e];
        const float4 pr = pos4[rc.x];
        const float4 pc = pos4[rc.y];
        const float rx = pr.x - pc.x, ry = pr.y - pc.y, rz = pr.z - pc.z;
        srce[e] = rc;
        sdr[e] = make_float4(rx, ry, rz, rx * rx + ry * ry + rz * rz);
    }

    const int c8 = lane & 7;   // channel chunk
    const int eo = lane >> 3;  // edge offset within group of 8

    float w1d8[8];
    {
        const float* wd = We1 + 128 * 64 + c8 * 8;
        const float4 wa = *(const float4*)wd;
        const float4 wb = *(const float4*)(wd + 4);
        w1d8[0] = wa.x; w1d8[1] = wa.y; w1d8[2] = wa.z; w1d8[3] = wa.w;
        w1d8[4] = wb.x; w1d8[5] = wb.y; w1d8[6] = wb.z; w1d8[7] = wb.w;
    }
    float be2v[4], bc1v[4], wc2v[4];
#pragma unroll
    for (int ni = 0; ni < 4; ++ni) {
        be2v[ni] = be2[ni * 16 + li];
        bc1v[ni] = bc1[ni * 16 + li];
        wc2v[ni] = Wc2[ni * 16 + li];
    }
    const float bc2s = bc2[0];

    // phase 2: stage m for own 16 edges (same-wave LDS rows; no barrier needed)
#pragma unroll
    for (int hh = 0; hh < 2; ++hh) {
        const int e = e0 + hh * 8 + eo;
        const int2 rc = srce[e];
        const float dv = sdr[e].w;
        const bf16x8 ar = *(const bf16x8*)(a1r + (size_t)rc.x * 64 + c8 * 8);
        const bf16x8 ac = *(const bf16x8*)(a1c + (size_t)rc.y * 64 + c8 * 8);
        bf16x8 out;
#pragma unroll
        for (int j = 0; j < 8; ++j) {
            const float m = b2f((unsigned short)ar[j]) + b2f((unsigned short)ac[j])
                          + dv * w1d8[j];
            out[j] = (short)f2b(silu_f(m));
        }
        *(bf16x8*)&sA[e][c8 * 8] = out;
    }

    // phase 3: GEMM2 (msg_pre = m @ We2)
    f32x4 acc[4];
#pragma unroll
    for (int ni = 0; ni < 4; ++ni) acc[ni] = (f32x4)(0.0f);
#pragma unroll
    for (int ks = 0; ks < 2; ++ks) {
        const bf16x8 af = *(const bf16x8*)&sA[e0 + li][ks * 32 + (lg << 3)];
#pragma unroll
        for (int ni = 0; ni < 4; ++ni) {
            const bf16x8 bf = *(const bf16x8*)(wfrag + (size_t)(ks * 4 + ni) * 512 + lane * 8);
            acc[ni] = MFMA16(af, bf, acc[ni]);
        }
    }

    // phase 4: msg = silu(msg_pre + be2) -> sA (own rows)
#pragma unroll
    for (int ni = 0; ni < 4; ++ni)
#pragma unroll
        for (int reg = 0; reg < 4; ++reg)
            sA[e0 + lg * 4 + reg][ni * 16 + li] = f2b(silu_f(acc[ni][reg] + be2v[ni]));

    // phase 5: msg quarter-sweep (rows non-decreasing)
    {
        float macc = 0.0f;
        int pr = srce[e0].x;
#pragma unroll
        for (int j = 0; j < 16; ++j) {
            const int re = srce[e0 + j].x;
            if (re != pr) {
                atomicAdd(&msg_agg[(size_t)pr * 64 + lane], macc);
                macc = 0.0f;
                pr = re;
            }
            macc += b2f(sA[e0 + j][lane]);
        }
        atomicAdd(&msg_agg[(size_t)pr * 64 + lane], macc);
    }

    // phase 6: GEMM3 (t = msg @ Wc1)
    f32x4 a3[4];
#pragma unroll
    for (int ni = 0; ni < 4; ++ni) a3[ni] = (f32x4)(0.0f);
#pragma unroll
    for (int ks = 0; ks < 2; ++ks) {
        const bf16x8 af = *(const bf16x8*)&sA[e0 + li][ks * 32 + (lg << 3)];
#pragma unroll
        for (int ni = 0; ni < 4; ++ni) {
            const bf16x8 bf = *(const bf16x8*)(wfrag + (size_t)(8 + ks * 4 + ni) * 512 + lane * 8);
            a3[ni] = MFMA16(af, bf, a3[ni]);
        }
    }

    // epilogue: cw[edge] = sum_c silu(t+bc1)[c] * Wc2[c]
    float sv[4];
#pragma unroll
    for (int reg = 0; reg < 4; ++reg) {
        float s = 0.0f;
#pragma unroll
        for (int ni = 0; ni < 4; ++ni)
            s += silu_f(a3[ni][reg] + bc1v[ni]) * wc2v[ni];
        sv[reg] = s;
    }
#pragma unroll
    for (int m = 1; m < 16; m <<= 1)
#pragma unroll
        for (int reg = 0; reg < 4; ++reg) sv[reg] += __shfl_xor(sv[reg], m, 64);
    if (li == 0) {
        float4 cv = make_float4(sv[0] + bc2s, sv[1] + bc2s, sv[2] + bc2s, sv[3] + bc2s);
        *(float4*)&scw[e0 + lg * 4] = cv;
    }
    __syncthreads();  // the only block barrier: publishes srce/sdr/scw to wave 0

    // phase 7: coord aggregation (wave 0): segmented scan, 1 atomic triplet/run
    if (tid < 64) {
        const float4 dr = sdr[tid];
        const int r_e = srce[tid].x;
        const float cw = scw[tid];
        float vx = dr.x * cw, vy = dr.y * cw, vz = dr.z * cw;
#pragma unroll
        for (int d = 1; d < 64; d <<= 1) {
            const float ox = __shfl_up(vx, d, 64);
            const float oy = __shfl_up(vy, d, 64);
            const float oz = __shfl_up(vz, d, 64);
            const int   orr = __shfl_up(r_e, d, 64);
            const bool add = (tid >= d) && (orr == r_e);
            vx += add ? ox : 0.0f;
            vy += add ? oy : 0.0f;
            vz += add ? oz : 0.0f;
        }
        const int rnext = __shfl_down(r_e, 1, 64);
        const bool last = (tid == 63) || (rnext != r_e);
        if (last) {
            atomicAdd(&pos_out[r_e * 3 + 0], vx);
            atomicAdd(&pos_out[r_e * 3 + 1], vy);
            atomicAdd(&pos_out[r_e * 3 + 2], vz);
        }
    }
}

// ---------------- K4: node MLP (one 64-node tile per block) ----------------

__global__ __launch_bounds__(256, 4) void node_kernel(
    const float* __restrict__ h, const float* __restrict__ msg_agg,
    const unsigned short* __restrict__ wfrag,
    const float* __restrict__ bn1, const float* __restrict__ bn2,
    float* __restrict__ h_out)
{
    __shared__ __align__(16) unsigned short sA[64][136];
    const int tid = threadIdx.x;
    const int lane = tid & 63, w = tid >> 6;
    const int t = blockIdx.x;
    const int li = lane & 15, lg = lane >> 4;

    float bn1v[4], bn2v[4];
#pragma unroll
    for (int ni = 0; ni < 4; ++ni) {
        bn1v[ni] = bn1[ni * 16 + li];
        bn2v[ni] = bn2[ni * 16 + li];
    }

    // stage own 16 rows of [h | msg] (K=128): cols 0-63 h, 64-127 msg
#pragma unroll
    for (int pass = 0; pass < 8; ++pass) {
        const int idx = pass * 64 + lane;          // 0..511
        const int n_loc = w * 16 + (idx >> 5);     // own rows
        const int c4 = idx & 31;                   // float4 chunk 0..31
        const int n = t * 64 + n_loc;
        float4 v = make_float4(0.f, 0.f, 0.f, 0.f);
        if (n < NN) {
            const float* src = (c4 < 16) ? &h[(size_t)n * 64 + c4 * 4]
                                         : &msg_agg[(size_t)n * 64 + (c4 - 16) * 4];
            v = *(const float4*)src;
        }
        bf16x4 p;
        p[0] = (short)f2b(v.x); p[1] = (short)f2b(v.y);
        p[2] = (short)f2b(v.z); p[3] = (short)f2b(v.w);
        *(bf16x4*)&sA[n_loc][c4 * 4] = p;
    }

    // GEMM1: K=128
    f32x4 acc[4];
#pragma unroll
    for (int ni = 0; ni < 4; ++ni) acc[ni] = (f32x4)(0.0f);
#pragma unroll
    for (int ks = 0; ks < 4; ++ks) {
        const bf16x8 afr = *(const bf16x8*)&sA[w * 16 + li][ks * 32 + (lg << 3)];
#pragma unroll
        for (int ni = 0; ni < 4; ++ni) {
            const bf16x8 bfr = *(const bf16x8*)(wfrag + (size_t)(16 + ks * 4 + ni) * 512 + lane * 8);
            acc[ni] = MFMA16(afr, bfr, acc[ni]);
        }
    }
    // silu + bn1 -> sA cols 0..63 (own rows)
#pragma unroll
    for (int ni = 0; ni < 4; ++ni)
#pragma unroll
        for (int reg = 0; reg < 4; ++reg)
            sA[w * 16 + lg * 4 + reg][ni * 16 + li] = f2b(silu_f(acc[ni][reg] + bn1v[ni]));

    // GEMM2: K=64
    f32x4 a2[4];
#pragma unroll
    for (int ni = 0; ni < 4; ++ni) a2[ni] = (f32x4)(0.0f);
#pragma unroll
    for (int ks = 0; ks < 2; ++ks) {
        const bf16x8 afr = *(const bf16x8*)&sA[w * 16 + li][ks * 32 + (lg << 3)];
#pragma unroll
        for (int ni = 0; ni < 4; ++ni) {
            const bf16x8 bfr = *(const bf16x8*)(wfrag + (size_t)(32 + ks * 4 + ni) * 512 + lane * 8);
            a2[ni] = MFMA16(afr, bfr, a2[ni]);
        }
    }
#pragma unroll
    for (int ni = 0; ni < 4; ++ni)
#pragma unroll
        for (int reg = 0; reg < 4; ++reg) {
            const int n = t * 64 + w * 16 + lg * 4 + reg;
            if (n < NN) h_out[(size_t)n * 64 + ni * 16 + li] = a2[ni][reg] + bn2v[ni];
        }
}

// ---------------- launch ----------------

extern "C" void kernel_launch(void* const* d_in, const int* in_sizes, int n_in,
                              void* d_out, int out_size, void* d_ws, size_t ws_size,
                              hipStream_t stream) {
    const float* h   = (const float*)d_in[0];
    const float* pos = (const float*)d_in[1];
    const int*   ei  = (const int*)d_in[2];
    const float* We1 = (const float*)d_in[3];
    const float* be1 = (const float*)d_in[4];
    const float* We2 = (const float*)d_in[5];
    const float* be2 = (const float*)d_in[6];
    const float* Wc1 = (const float*)d_in[7];
    const float* bc1 = (const float*)d_in[8];
    const float* Wc2 = (const float*)d_in[9];
    const float* bc2 = (const float*)d_in[10];
    const float* Wn1 = (const float*)d_in[11];
    const float* bn1 = (const float*)d_in[12];
    const float* Wn2 = (const float*)d_in[13];
    const float* bn2 = (const float*)d_in[14];

    unsigned short* a1r   = (unsigned short*)d_ws;            // [N*64] bf16
    unsigned short* a1c   = a1r + (size_t)NN * 64;            // [N*64] bf16
    unsigned short* wfrag = a1c + (size_t)NN * 64;            // 40 frags * 512
    int2* sorted_rc = (int2*)(wfrag + 40 * 512);              // [E]
    int*  gh        = (int*)(sorted_rc + NE);                 // 64000 + 128 aux
    float4* pos4    = (float4*)(gh + GHN + 128);              // [N]

    float* msg_agg = (float*)d_out;                           // reused as h_out
    float* pos_out = msg_agg + (size_t)NN * 64;

    prep_kernel<<<K1_GRID, 256, 0, stream>>>(pos, We2, Wc1, Wn1, Wn2, ei,
                                             wfrag, gh, msg_agg, pos_out, pos4);
    sort_fused_kernel<<<K2_GRID, 256, 0, stream>>>(h, be1, We1, ei, gh,
                                                   a1r, a1c, sorted_rc);
    egnn_edge_kernel<<<ETILE, 256, 0, stream>>>(pos4, sorted_rc, a1r, a1c, We1, wfrag,
                                                be2, bc1, Wc2, bc2, msg_agg, pos_out);
    node_kernel<<<782, 256, 0, stream>>>(h, msg_agg, wfrag, bn1, bn2, msg_agg);
}

// Round 12
// 263.144 us; speedup vs baseline: 1.5254x; 1.5254x over previous
//
#include <hip/hip_runtime.h>

// EGNN conv: N=50000, E=800000, C=64.
// Round 19 == round 14 resubmitted (rounds 5/7/8/9/10/11 benches were all
// GPUAcquisitionTimeouts; this build has never been measured).
// Base = round-11 verified 199.6us build, plus two small changes:
// (1) scan+scat fused into one 313-block kernel (all co-resident, ~1KB LDS,
//     waiters after waitees -- the verified lookback regime). 6 -> 5 dispatches.
// (2) edge kernel __launch_bounds__ 6 -> 8 blocks/CU (VGPR 36, LDS 12.3KB both
//     fit): fills the 22% memory-stall gap seen at VALUBusy 78% / occ 60%.
// Round-13 lesson (counters): big-LDS spin-packed fusion idles the machine
// (260us @ VALUBusy 1%); only small co-resident spin groups are safe.

#define NN 50000
#define NE 800000
#define ETILE 12500         // NE/64

// sort geometry
#define SBLK 250            // passA/scat blocks
#define SCHUNK 3200         // NE/SBLK edges per block
#define NBUK 196            // buckets = ceil(50000/256)
#define GHN 64000           // 256*SBLK counters
#define SCAN_NB 63          // 63 blocks * 256 thr * 4 elems = 64512 >= 64000

typedef __attribute__((ext_vector_type(8))) short bf16x8;
typedef __attribute__((ext_vector_type(4))) short bf16x4;
typedef __attribute__((ext_vector_type(4))) float f32x4;

#define MFMA16(a, b, c) __builtin_amdgcn_mfma_f32_16x16x32_bf16(a, b, c, 0, 0, 0)

__device__ __forceinline__ unsigned short f2b(float x) {
    union { float f; unsigned u; } v; v.f = x;
    return (unsigned short)((v.u + 0x8000u) >> 16);
}
__device__ __forceinline__ float b2f(unsigned short b) {
    union { unsigned u; float f; } v; v.u = ((unsigned)b) << 16; return v.f;
}
__device__ __forceinline__ float silu_f(float x) {
    return x * __builtin_amdgcn_rcpf(1.0f + __expf(-x));
}

// wfrag layout (40 frags x 512 bf16): 0..7 We2, 8..15 Wc1, 16..31 Wn1,
// 32..39 Wn2. node_pre loads We1 directly from global (L2-resident).

// ---------------- K1: passA || frag || node_pre || zero || copy ----------------

#define P1_A 250
#define P1_FRAG 10
#define P1_NPRE 782
#define P1_ZERO 200
#define P1_COPY 16
#define P1_FRAG0 (P1_A)
#define P1_NPRE0 (P1_A + P1_FRAG)
#define P1_ZERO0 (P1_NPRE0 + P1_NPRE)
#define P1_COPY0 (P1_ZERO0 + P1_ZERO)
#define K1_GRID (P1_COPY0 + P1_COPY)

__global__ __launch_bounds__(256, 4) void prep_kernel(
    const float* __restrict__ h, const float* __restrict__ pos,
    const float* __restrict__ be1,
    const float* __restrict__ We1, const float* __restrict__ We2,
    const float* __restrict__ Wc1, const float* __restrict__ Wn1,
    const float* __restrict__ Wn2, const int* __restrict__ ei,
    unsigned short* __restrict__ wfrag, int* __restrict__ gh,
    unsigned short* __restrict__ a1r, unsigned short* __restrict__ a1c,
    float* __restrict__ msg_agg, float* __restrict__ pos_out,
    float4* __restrict__ pos4)
{
    __shared__ __align__(16) unsigned short sH[64][72];
    __shared__ __align__(16) unsigned short sT[4][16][72];
    __shared__ int lh[256];
    const int b = blockIdx.x, tid = threadIdx.x;
    if (b < P1_A) {
        // coarse bucket histogram for this block's 3200 edges
        lh[tid] = 0;
        __syncthreads();
        const int base = b * SCHUNK;
        for (int i = base + tid; i < base + SCHUNK; i += 256)
            atomicAdd(&lh[ei[i] >> 8], 1);
        __syncthreads();
        gh[tid * SBLK + b] = lh[tid];   // bucket-major [256][SBLK]
    } else if (b < P1_NPRE0) {
        const int lane = tid & 63, w = tid >> 6;
        const int li = lane & 15, lg = lane >> 4;
        const int f = (b - P1_FRAG0) * 4 + w;  // 0..39
        const float* W; int g;
        if (f < 8)       { W = We2; g = f; }
        else if (f < 16) { W = Wc1; g = f - 8; }
        else if (f < 32) { W = Wn1; g = f - 16; }
        else             { W = Wn2; g = f - 32; }
        const int ks = g >> 2, ni = g & 3;
        const int n = ni * 16 + li, kb = ks * 32 + (lg << 3);
        bf16x8 v;
#pragma unroll
        for (int j = 0; j < 8; ++j) v[j] = (short)f2b(W[(kb + j) * 64 + n]);
        *(bf16x8*)(wfrag + (size_t)f * 512 + lane * 8) = v;
    } else if (b < P1_ZERO0) {
        // node_pre: one 64-node tile per block; wave w owns rows [w*16, w*16+16)
        const int lane = tid & 63, w = tid >> 6;
        const int li = lane & 15, lg = lane >> 4;
        const int t = b - P1_NPRE0;
        const int c4 = lane & 15, rsub = lane >> 4;
#pragma unroll
        for (int pass = 0; pass < 4; ++pass) {
            const int n_loc = w * 16 + pass * 4 + rsub;
            const int n = t * 64 + n_loc;
            float4 hv = make_float4(0.f, 0.f, 0.f, 0.f);
            if (n < NN) hv = *(const float4*)&h[(size_t)n * 64 + c4 * 4];
            bf16x4 hp;
            hp[0] = (short)f2b(hv.x); hp[1] = (short)f2b(hv.y);
            hp[2] = (short)f2b(hv.z); hp[3] = (short)f2b(hv.w);
            *(bf16x4*)&sH[n_loc][c4 * 4] = hp;   // wave-private rows
        }
        float be1v[4];
#pragma unroll
        for (int ni = 0; ni < 4; ++ni) be1v[ni] = be1[ni * 16 + li];

#pragma unroll
        for (int half = 0; half < 2; ++half) {
            unsigned short* out = half ? a1c : a1r;
            f32x4 acc[4];
#pragma unroll
            for (int ni = 0; ni < 4; ++ni) acc[ni] = (f32x4)(0.0f);
#pragma unroll
            for (int ks = 0; ks < 2; ++ks) {
                const bf16x8 afr = *(const bf16x8*)&sH[w * 16 + li][ks * 32 + (lg << 3)];
#pragma unroll
                for (int ni = 0; ni < 4; ++ni) {
                    // We1 B-fragment direct from global (L2-resident):
                    const float* Wp = We1 +
                        (size_t)(half * 64 + ks * 32 + (lg << 3)) * 64 + ni * 16 + li;
                    bf16x8 bfr;
#pragma unroll
                    for (int j = 0; j < 8; ++j) bfr[j] = (short)f2b(Wp[(size_t)j * 64]);
                    acc[ni] = MFMA16(afr, bfr, acc[ni]);
                }
            }
            // transpose via wave-private sT, then coalesced dwordx4 stores
#pragma unroll
            for (int ni = 0; ni < 4; ++ni)
#pragma unroll
                for (int reg = 0; reg < 4; ++reg)
                    sT[w][lg * 4 + reg][ni * 16 + li] =
                        f2b(acc[ni][reg] + (half ? 0.f : be1v[ni]));
#pragma unroll
            for (int pass = 0; pass < 2; ++pass) {
                const int rr = pass * 8 + (lane >> 3);
                const int n = t * 64 + w * 16 + rr;
                const bf16x8 v = *(const bf16x8*)&sT[w][rr][(lane & 7) * 8];
                if (n < NN) *(bf16x8*)&out[(size_t)n * 64 + (lane & 7) * 8] = v;
            }
        }
    } else if (b < P1_COPY0) {
        float4* dst = (float4*)msg_agg;
        int i = (b - P1_ZERO0) * 256 + tid;
        for (; i < NN * 16; i += P1_ZERO * 256) dst[i] = make_float4(0.f, 0.f, 0.f, 0.f);
    } else {
        if (b == P1_COPY0 && tid < 128) gh[GHN + tid] = 0;  // scan aux + done ctr
        int i = (b - P1_COPY0) * 256 + tid;
        for (; i < 37500 + NN; i += P1_COPY * 256) {
            if (i < 37500) {
                ((float4*)pos_out)[i] = ((const float4*)pos)[i];
            } else {
                const int n = i - 37500;
                pos4[n] = make_float4(pos[3 * n], pos[3 * n + 1], pos[3 * n + 2], 0.f);
            }
        }
    }
}

// ---------------- K2: scanscat = scan(63) + scat(250), all co-resident ----------------
// aux[0..63) aggregates, aux[63..126) flags, aux[126]=scan_done counter.
// 313 blocks x ~1KB LDS: trivially co-resident; scat spins only for the
// scan's ~4us. Verified lookback-regime mechanism (rounds 8/11/13-functional).

#define SS_SCAN 63
#define SS_GRID 313

__global__ __launch_bounds__(256) void scanscat_kernel(
    const int* __restrict__ ei, int* __restrict__ gh,
    int2* __restrict__ sorted_rc)
{
    __shared__ int wsum[4];
    __shared__ int s_prefix;
    __shared__ int off[256];
    const int b = blockIdx.x, tid = threadIdx.x;
    int* aux = gh + GHN;
    const int lane = tid & 63, wid = tid >> 6;

    if (b < SS_SCAN) {
        // ---- scan over GHN elems, 4 per thread ----
        const int base4 = (b * 256 + tid) * 4;
        int vv[4];
#pragma unroll
        for (int i = 0; i < 4; ++i) {
            const int idx = base4 + i;
            vv[i] = (idx < GHN) ? gh[idx] : 0;
        }
        const int s = vv[0] + vv[1] + vv[2] + vv[3];
        int inc = s;
#pragma unroll
        for (int d = 1; d < 64; d <<= 1) {
            const int o = __shfl_up(inc, d, 64);
            if (lane >= d) inc += o;
        }
        if (lane == 63) wsum[wid] = inc;
        __syncthreads();
        if (tid == 0) {
            int run = 0;
#pragma unroll
            for (int i = 0; i < 4; ++i) {
                const int tmp = wsum[i]; wsum[i] = run; run += tmp;
            }
            __hip_atomic_store(&aux[b], run, __ATOMIC_RELAXED, __HIP_MEMORY_SCOPE_AGENT);
            __hip_atomic_store(&aux[SCAN_NB + b], 1, __ATOMIC_RELEASE, __HIP_MEMORY_SCOPE_AGENT);
        }
        __syncthreads();
        const int thr_excl = wsum[wid] + inc - s;
        if (tid < 64) {
            int s2 = 0;
            if (tid < b) {
                while (__hip_atomic_load(&aux[SCAN_NB + tid], __ATOMIC_ACQUIRE,
                                         __HIP_MEMORY_SCOPE_AGENT) == 0) {
                    __builtin_amdgcn_s_sleep(2);
                }
                s2 = __hip_atomic_load(&aux[tid], __ATOMIC_RELAXED, __HIP_MEMORY_SCOPE_AGENT);
            }
#pragma unroll
            for (int m = 1; m < 64; m <<= 1) s2 += __shfl_xor(s2, m, 64);
            if (tid == 0) s_prefix = s2;
        }
        __syncthreads();
        int run = s_prefix + thr_excl;
#pragma unroll
        for (int i = 0; i < 4; ++i) {
            const int idx = base4 + i;
            if (idx < GHN) gh[idx] = run;
            run += vv[i];
        }
        __syncthreads();
        if (tid == 0)
            __hip_atomic_fetch_add(&aux[126], 1, __ATOMIC_RELEASE, __HIP_MEMORY_SCOPE_AGENT);
    } else {
        // ---- scat: wait for all scan blocks, then scatter to bucket regions ----
        while (__hip_atomic_load(&aux[126], __ATOMIC_ACQUIRE,
                                 __HIP_MEMORY_SCOPE_AGENT) != SS_SCAN) {
            __builtin_amdgcn_s_sleep(2);
        }
        const int bb = b - SS_SCAN;
        off[tid] = gh[tid * SBLK + bb];
        __syncthreads();
        const int base = bb * SCHUNK;
        for (int i = base + tid; i < base + SCHUNK; i += 256) {
            const int r = ei[i];
            const int c = ei[NE + i];
            const int p = atomicAdd(&off[r >> 8], 1);
            sorted_rc[p] = make_int2(r, c);
        }
    }
}

// ---------------- K3: per-bucket counting sort (bin = row & 255) ----------------

__global__ __launch_bounds__(256) void bsort_kernel(const int* __restrict__ gh,
                                                    int2* __restrict__ sorted_rc) {
    __shared__ int h2[256];
    __shared__ int sc[256];
    __shared__ int off2[256];
    __shared__ __align__(16) int2 stage[4096];
    const int k = blockIdx.x, t = threadIdx.x;
    const int start = gh[k * SBLK];
    const int end   = gh[(k + 1) * SBLK];
    for (int cb = start; cb < end; cb += 4096) {
        const int cnt = min(4096, end - cb);
        h2[t] = 0;
        __syncthreads();
        int2 le[16];
        int nloc = 0;
#pragma unroll
        for (int jj = 0; jj < 16; ++jj) {
            const int j = jj * 256 + t;
            if (j < cnt) {
                const int2 e = sorted_rc[cb + j];
                le[jj] = e;
                atomicAdd(&h2[e.x & 255], 1);
                nloc = jj + 1;
            }
        }
        __syncthreads();
        sc[t] = h2[t];
        __syncthreads();
        for (int d = 1; d < 256; d <<= 1) {
            const int v = (t >= d) ? sc[t - d] : 0;
            __syncthreads();
            sc[t] += v;
            __syncthreads();
        }
        off2[t] = sc[t] - h2[t];   // exclusive prefix
        __syncthreads();
#pragma unroll
        for (int jj = 0; jj < 16; ++jj) {
            if (jj < nloc) {
                const int rank = atomicAdd(&off2[le[jj].x & 255], 1);
                stage[rank] = le[jj];
            }
        }
        __syncthreads();
        for (int j = t; j < cnt; j += 256) sorted_rc[cb + j] = stage[j];
        __syncthreads();
    }
}

// ---------------- K4: edge kernel (round-8/11 body, occupancy 6 -> 8) ----------------

__global__ __launch_bounds__(256, 8) void egnn_edge_kernel(
    const float4* __restrict__ pos4, const int2* __restrict__ sorted_rc,
    const unsigned short* __restrict__ a1r, const unsigned short* __restrict__ a1c,
    const float* __restrict__ We1,  // row 128 = dist weights
    const unsigned short* __restrict__ wfrag,
    const float* __restrict__ be2, const float* __restrict__ bc1,
    const float* __restrict__ Wc2, const float* __restrict__ bc2,
    float* __restrict__ msg_agg, float* __restrict__ pos_out)
{
    __shared__ __align__(16) unsigned short sA[64][80];  // [edge][chan]
    __shared__ __align__(8) int2 srce[64];               // (row,col)
    __shared__ __align__(16) float4 sdr[64];             // (rx,ry,rz,dsq)
    __shared__ float scw[64];

    const int tid = threadIdx.x;
    const int lane = tid & 63, w = tid >> 6;
    const int li = lane & 15, lg = lane >> 4;
    const int tile = blockIdx.x;
    const int e0 = w * 16;

    // phase 0 (per wave, lanes 0-15): endpoints + relpos for own 16 edges
    if (lane < 16) {
        const int e = e0 + lane;
        const int2 rc = sorted_rc[tile * 64 + e];
        const float4 pr = pos4[rc.x];
        const float4 pc = pos4[rc.y];
        const float rx = pr.x - pc.x, ry = pr.y - pc.y, rz = pr.z - pc.z;
        srce[e] = rc;
        sdr[e] = make_float4(rx, ry, rz, rx * rx + ry * ry + rz * rz);
    }

    const int c8 = lane & 7;   // channel chunk
    const int eo = lane >> 3;  // edge offset within group of 8

    float w1d8[8];
    {
        const float* wd = We1 + 128 * 64 + c8 * 8;
        const float4 wa = *(const float4*)wd;
        const float4 wb = *(const float4*)(wd + 4);
        w1d8[0] = wa.x; w1d8[1] = wa.y; w1d8[2] = wa.z; w1d8[3] = wa.w;
        w1d8[4] = wb.x; w1d8[5] = wb.y; w1d8[6] = wb.z; w1d8[7] = wb.w;
    }
    float be2v[4], bc1v[4], wc2v[4];
#pragma unroll
    for (int ni = 0; ni < 4; ++ni) {
        be2v[ni] = be2[ni * 16 + li];
        bc1v[ni] = bc1[ni * 16 + li];
        wc2v[ni] = Wc2[ni * 16 + li];
    }
    const float bc2s = bc2[0];

    // phase 2: stage m for own 16 edges (same-wave LDS rows; no barrier needed)
#pragma unroll
    for (int hh = 0; hh < 2; ++hh) {
        const int e = e0 + hh * 8 + eo;
        const int2 rc = srce[e];
        const float dv = sdr[e].w;
        const bf16x8 ar = *(const bf16x8*)(a1r + (size_t)rc.x * 64 + c8 * 8);
        const bf16x8 ac = *(const bf16x8*)(a1c + (size_t)rc.y * 64 + c8 * 8);
        bf16x8 out;
#pragma unroll
        for (int j = 0; j < 8; ++j) {
            const float m = b2f((unsigned short)ar[j]) + b2f((unsigned short)ac[j])
                          + dv * w1d8[j];
            out[j] = (short)f2b(silu_f(m));
        }
        *(bf16x8*)&sA[e][c8 * 8] = out;
    }

    // phase 3: GEMM2 (msg_pre = m @ We2)
    f32x4 acc[4];
#pragma unroll
    for (int ni = 0; ni < 4; ++ni) acc[ni] = (f32x4)(0.0f);
#pragma unroll
    for (int ks = 0; ks < 2; ++ks) {
        const bf16x8 af = *(const bf16x8*)&sA[e0 + li][ks * 32 + (lg << 3)];
#pragma unroll
        for (int ni = 0; ni < 4; ++ni) {
            const bf16x8 bf = *(const bf16x8*)(wfrag + (size_t)(ks * 4 + ni) * 512 + lane * 8);
            acc[ni] = MFMA16(af, bf, acc[ni]);
        }
    }

    // phase 4: msg = silu(msg_pre + be2) -> sA (own rows)
#pragma unroll
    for (int ni = 0; ni < 4; ++ni)
#pragma unroll
        for (int reg = 0; reg < 4; ++reg)
            sA[e0 + lg * 4 + reg][ni * 16 + li] = f2b(silu_f(acc[ni][reg] + be2v[ni]));

    // phase 5: msg quarter-sweep (rows non-decreasing)
    {
        float macc = 0.0f;
        int pr = srce[e0].x;
#pragma unroll
        for (int j = 0; j < 16; ++j) {
            const int re = srce[e0 + j].x;
            if (re != pr) {
                atomicAdd(&msg_agg[(size_t)pr * 64 + lane], macc);
                macc = 0.0f;
                pr = re;
            }
            macc += b2f(sA[e0 + j][lane]);
        }
        atomicAdd(&msg_agg[(size_t)pr * 64 + lane], macc);
    }

    // phase 6: GEMM3 (t = msg @ Wc1)
    f32x4 a3[4];
#pragma unroll
    for (int ni = 0; ni < 4; ++ni) a3[ni] = (f32x4)(0.0f);
#pragma unroll
    for (int ks = 0; ks < 2; ++ks) {
        const bf16x8 af = *(const bf16x8*)&sA[e0 + li][ks * 32 + (lg << 3)];
#pragma unroll
        for (int ni = 0; ni < 4; ++ni) {
            const bf16x8 bf = *(const bf16x8*)(wfrag + (size_t)(8 + ks * 4 + ni) * 512 + lane * 8);
            a3[ni] = MFMA16(af, bf, a3[ni]);
        }
    }

    // epilogue: cw[edge] = sum_c silu(t+bc1)[c] * Wc2[c]
    float sv[4];
#pragma unroll
    for (int reg = 0; reg < 4; ++reg) {
        float s = 0.0f;
#pragma unroll
        for (int ni = 0; ni < 4; ++ni)
            s += silu_f(a3[ni][reg] + bc1v[ni]) * wc2v[ni];
        sv[reg] = s;
    }
#pragma unroll
    for (int m = 1; m < 16; m <<= 1)
#pragma unroll
        for (int reg = 0; reg < 4; ++reg) sv[reg] += __shfl_xor(sv[reg], m, 64);
    if (li == 0) {
        float4 cv = make_float4(sv[0] + bc2s, sv[1] + bc2s, sv[2] + bc2s, sv[3] + bc2s);
        *(float4*)&scw[e0 + lg * 4] = cv;
    }
    __syncthreads();  // the only block barrier: publishes srce/sdr/scw to wave 0

    // phase 7: coord aggregation (wave 0): segmented scan, 1 atomic triplet/run
    if (tid < 64) {
        const float4 dr = sdr[tid];
        const int r_e = srce[tid].x;
        const float cw = scw[tid];
        float vx = dr.x * cw, vy = dr.y * cw, vz = dr.z * cw;
#pragma unroll
        for (int d = 1; d < 64; d <<= 1) {
            const float ox = __shfl_up(vx, d, 64);
            const float oy = __shfl_up(vy, d, 64);
            const float oz = __shfl_up(vz, d, 64);
            const int   orr = __shfl_up(r_e, d, 64);
            const bool add = (tid >= d) && (orr == r_e);
            vx += add ? ox : 0.0f;
            vy += add ? oy : 0.0f;
            vz += add ? oz : 0.0f;
        }
        const int rnext = __shfl_down(r_e, 1, 64);
        const bool last = (tid == 63) || (rnext != r_e);
        if (last) {
            atomicAdd(&pos_out[r_e * 3 + 0], vx);
            atomicAdd(&pos_out[r_e * 3 + 1], vy);
            atomicAdd(&pos_out[r_e * 3 + 2], vz);
        }
    }
}

// ---------------- K5: node MLP (one 64-node tile per block) ----------------

__global__ __launch_bounds__(256, 4) void node_kernel(
    const float* __restrict__ h, const float* __restrict__ msg_agg,
    const unsigned short* __restrict__ wfrag,
    const float* __restrict__ bn1, const float* __restrict__ bn2,
    float* __restrict__ h_out)
{
    __shared__ __align__(16) unsigned short sA[64][136];
    const int tid = threadIdx.x;
    const int lane = tid & 63, w = tid >> 6;
    const int t = blockIdx.x;
    const int li = lane & 15, lg = lane >> 4;

    float bn1v[4], bn2v[4];
#pragma unroll
    for (int ni = 0; ni < 4; ++ni) {
        bn1v[ni] = bn1[ni * 16 + li];
        bn2v[ni] = bn2[ni * 16 + li];
    }

    // stage own 16 rows of [h | msg] (K=128): cols 0-63 h, 64-127 msg
#pragma unroll
    for (int pass = 0; pass < 8; ++pass) {
        const int idx = pass * 64 + lane;          // 0..511
        const int n_loc = w * 16 + (idx >> 5);     // own rows
        const int c4 = idx & 31;                   // float4 chunk 0..31
        const int n = t * 64 + n_loc;
        float4 v = make_float4(0.f, 0.f, 0.f, 0.f);
        if (n < NN) {
            const float* src = (c4 < 16) ? &h[(size_t)n * 64 + c4 * 4]
                                         : &msg_agg[(size_t)n * 64 + (c4 - 16) * 4];
            v = *(const float4*)src;
        }
        bf16x4 p;
        p[0] = (short)f2b(v.x); p[1] = (short)f2b(v.y);
        p[2] = (short)f2b(v.z); p[3] = (short)f2b(v.w);
        *(bf16x4*)&sA[n_loc][c4 * 4] = p;
    }

    // GEMM1: K=128
    f32x4 acc[4];
#pragma unroll
    for (int ni = 0; ni < 4; ++ni) acc[ni] = (f32x4)(0.0f);
#pragma unroll
    for (int ks = 0; ks < 4; ++ks) {
        const bf16x8 afr = *(const bf16x8*)&sA[w * 16 + li][ks * 32 + (lg << 3)];
#pragma unroll
        for (int ni = 0; ni < 4; ++ni) {
            const bf16x8 bfr = *(const bf16x8*)(wfrag + (size_t)(16 + ks * 4 + ni) * 512 + lane * 8);
            acc[ni] = MFMA16(afr, bfr, acc[ni]);
        }
    }
    // silu + bn1 -> sA cols 0..63 (own rows)
#pragma unroll
    for (int ni = 0; ni < 4; ++ni)
#pragma unroll
        for (int reg = 0; reg < 4; ++reg)
            sA[w * 16 + lg * 4 + reg][ni * 16 + li] = f2b(silu_f(acc[ni][reg] + bn1v[ni]));

    // GEMM2: K=64
    f32x4 a2[4];
#pragma unroll
    for (int ni = 0; ni < 4; ++ni) a2[ni] = (f32x4)(0.0f);
#pragma unroll
    for (int ks = 0; ks < 2; ++ks) {
        const bf16x8 afr = *(const bf16x8*)&sA[w * 16 + li][ks * 32 + (lg << 3)];
#pragma unroll
        for (int ni = 0; ni < 4; ++ni) {
            const bf16x8 bfr = *(const bf16x8*)(wfrag + (size_t)(32 + ks * 4 + ni) * 512 + lane * 8);
            a2[ni] = MFMA16(afr, bfr, a2[ni]);
        }
    }
#pragma unroll
    for (int ni = 0; ni < 4; ++ni)
#pragma unroll
        for (int reg = 0; reg < 4; ++reg) {
            const int n = t * 64 + w * 16 + lg * 4 + reg;
            if (n < NN) h_out[(size_t)n * 64 + ni * 16 + li] = a2[ni][reg] + bn2v[ni];
        }
}

// ---------------- launch ----------------

extern "C" void kernel_launch(void* const* d_in, const int* in_sizes, int n_in,
                              void* d_out, int out_size, void* d_ws, size_t ws_size,
                              hipStream_t stream) {
    const float* h   = (const float*)d_in[0];
    const float* pos = (const float*)d_in[1];
    const int*   ei  = (const int*)d_in[2];
    const float* We1 = (const float*)d_in[3];
    const float* be1 = (const float*)d_in[4];
    const float* We2 = (const float*)d_in[5];
    const float* be2 = (const float*)d_in[6];
    const float* Wc1 = (const float*)d_in[7];
    const float* bc1 = (const float*)d_in[8];
    const float* Wc2 = (const float*)d_in[9];
    const float* bc2 = (const float*)d_in[10];
    const float* Wn1 = (const float*)d_in[11];
    const float* bn1 = (const float*)d_in[12];
    const float* Wn2 = (const float*)d_in[13];
    const float* bn2 = (const float*)d_in[14];

    unsigned short* a1r   = (unsigned short*)d_ws;            // [N*64] bf16
    unsigned short* a1c   = a1r + (size_t)NN * 64;            // [N*64] bf16
    unsigned short* wfrag = a1c + (size_t)NN * 64;            // 40 frags * 512
    int2* sorted_rc = (int2*)(wfrag + 40 * 512);              // [E]
    int*  gh        = (int*)(sorted_rc + NE);                 // 64000 + 128 aux
    float4* pos4    = (float4*)(gh + GHN + 128);              // [N]

    float* msg_agg = (float*)d_out;                           // reused as h_out
    float* pos_out = msg_agg + (size_t)NN * 64;

    prep_kernel<<<K1_GRID, 256, 0, stream>>>(h, pos, be1, We1, We2, Wc1, Wn1, Wn2,
                                             ei, wfrag, gh, a1r, a1c,
                                             msg_agg, pos_out, pos4);
    scanscat_kernel<<<SS_GRID, 256, 0, stream>>>(ei, gh, sorted_rc);
    bsort_kernel<<<NBUK, 256, 0, stream>>>(gh, sorted_rc);
    egnn_edge_kernel<<<ETILE, 256, 0, stream>>>(pos4, sorted_rc, a1r, a1c, We1, wfrag,
                                                be2, bc1, Wc2, bc2, msg_agg, pos_out);
    node_kernel<<<782, 256, 0, stream>>>(h, msg_agg, wfrag, bn1, bn2, msg_agg);
}

// Round 13
// 199.645 us; speedup vs baseline: 2.0105x; 1.3181x over previous
//
#include <hip/hip_runtime.h>

// EGNN conv: N=50000, E=800000, C=64.
// Round 20: REVERT the scanscat spin-fusion. Round-14 measurement (263us):
// scanscat ran 85.6us at VALUBusy 0.27% / occ 12% -- 64000 threads mass-polling
// ONE agent-scope flag line poisons the fabric and starves the 63 scan blocks
// (standalone scan+scat were ~25us). Lesson: lookback works because each flag
// has <=63 single-lane waiters; mass spin on one flag costs ~60us; a 4us
// dispatch boundary is strictly cheaper.
// Structure = round-11 verified 199.6us 6-dispatch pipeline; the only retained
// round-14 delta is edge __launch_bounds__(256,8) (edge absent from round-14
// top-5 => <84us, regression fully attributed to scanscat => bump safe; this
// round isolates it).

#define NN 50000
#define NE 800000
#define ETILE 12500         // NE/64

// sort geometry
#define SBLK 250            // passA/scat blocks
#define SCHUNK 3200         // NE/SBLK edges per block
#define NBUK 196            // buckets = ceil(50000/256)
#define GHN 64000           // 256*SBLK counters
#define SCAN_NB 63          // 63*1024 >= 64000

typedef __attribute__((ext_vector_type(8))) short bf16x8;
typedef __attribute__((ext_vector_type(4))) short bf16x4;
typedef __attribute__((ext_vector_type(4))) float f32x4;

#define MFMA16(a, b, c) __builtin_amdgcn_mfma_f32_16x16x32_bf16(a, b, c, 0, 0, 0)

__device__ __forceinline__ unsigned short f2b(float x) {
    union { float f; unsigned u; } v; v.f = x;
    return (unsigned short)((v.u + 0x8000u) >> 16);
}
__device__ __forceinline__ float b2f(unsigned short b) {
    union { unsigned u; float f; } v; v.u = ((unsigned)b) << 16; return v.f;
}
__device__ __forceinline__ float silu_f(float x) {
    return x * __builtin_amdgcn_rcpf(1.0f + __expf(-x));
}

// wfrag layout (40 frags x 512 bf16): 0..7 We2, 8..15 Wc1, 16..31 Wn1,
// 32..39 Wn2. node_pre loads We1 directly from global (L2-resident).

// ---------------- K1: passA || frag || node_pre || zero || copy ----------------

#define P1_A 250
#define P1_FRAG 10
#define P1_NPRE 782
#define P1_ZERO 200
#define P1_COPY 16
#define P1_FRAG0 (P1_A)
#define P1_NPRE0 (P1_A + P1_FRAG)
#define P1_ZERO0 (P1_NPRE0 + P1_NPRE)
#define P1_COPY0 (P1_ZERO0 + P1_ZERO)
#define K1_GRID (P1_COPY0 + P1_COPY)

__global__ __launch_bounds__(256, 4) void prep_kernel(
    const float* __restrict__ h, const float* __restrict__ pos,
    const float* __restrict__ be1,
    const float* __restrict__ We1, const float* __restrict__ We2,
    const float* __restrict__ Wc1, const float* __restrict__ Wn1,
    const float* __restrict__ Wn2, const int* __restrict__ ei,
    unsigned short* __restrict__ wfrag, int* __restrict__ gh,
    unsigned short* __restrict__ a1r, unsigned short* __restrict__ a1c,
    float* __restrict__ msg_agg, float* __restrict__ pos_out,
    float4* __restrict__ pos4)
{
    __shared__ __align__(16) unsigned short sH[64][72];
    __shared__ __align__(16) unsigned short sT[4][16][72];
    __shared__ int lh[256];
    const int b = blockIdx.x, tid = threadIdx.x;
    if (b < P1_A) {
        // coarse bucket histogram for this block's 3200 edges
        lh[tid] = 0;
        __syncthreads();
        const int base = b * SCHUNK;
        for (int i = base + tid; i < base + SCHUNK; i += 256)
            atomicAdd(&lh[ei[i] >> 8], 1);
        __syncthreads();
        gh[tid * SBLK + b] = lh[tid];   // bucket-major [256][SBLK]
    } else if (b < P1_NPRE0) {
        const int lane = tid & 63, w = tid >> 6;
        const int li = lane & 15, lg = lane >> 4;
        const int f = (b - P1_FRAG0) * 4 + w;  // 0..39
        const float* W; int g;
        if (f < 8)       { W = We2; g = f; }
        else if (f < 16) { W = Wc1; g = f - 8; }
        else if (f < 32) { W = Wn1; g = f - 16; }
        else             { W = Wn2; g = f - 32; }
        const int ks = g >> 2, ni = g & 3;
        const int n = ni * 16 + li, kb = ks * 32 + (lg << 3);
        bf16x8 v;
#pragma unroll
        for (int j = 0; j < 8; ++j) v[j] = (short)f2b(W[(kb + j) * 64 + n]);
        *(bf16x8*)(wfrag + (size_t)f * 512 + lane * 8) = v;
    } else if (b < P1_ZERO0) {
        // node_pre: one 64-node tile per block; wave w owns rows [w*16, w*16+16)
        const int lane = tid & 63, w = tid >> 6;
        const int li = lane & 15, lg = lane >> 4;
        const int t = b - P1_NPRE0;
        const int c4 = lane & 15, rsub = lane >> 4;
#pragma unroll
        for (int pass = 0; pass < 4; ++pass) {
            const int n_loc = w * 16 + pass * 4 + rsub;
            const int n = t * 64 + n_loc;
            float4 hv = make_float4(0.f, 0.f, 0.f, 0.f);
            if (n < NN) hv = *(const float4*)&h[(size_t)n * 64 + c4 * 4];
            bf16x4 hp;
            hp[0] = (short)f2b(hv.x); hp[1] = (short)f2b(hv.y);
            hp[2] = (short)f2b(hv.z); hp[3] = (short)f2b(hv.w);
            *(bf16x4*)&sH[n_loc][c4 * 4] = hp;   // wave-private rows
        }
        float be1v[4];
#pragma unroll
        for (int ni = 0; ni < 4; ++ni) be1v[ni] = be1[ni * 16 + li];

#pragma unroll
        for (int half = 0; half < 2; ++half) {
            unsigned short* out = half ? a1c : a1r;
            f32x4 acc[4];
#pragma unroll
            for (int ni = 0; ni < 4; ++ni) acc[ni] = (f32x4)(0.0f);
#pragma unroll
            for (int ks = 0; ks < 2; ++ks) {
                const bf16x8 afr = *(const bf16x8*)&sH[w * 16 + li][ks * 32 + (lg << 3)];
#pragma unroll
                for (int ni = 0; ni < 4; ++ni) {
                    // We1 B-fragment direct from global (L2-resident):
                    const float* Wp = We1 +
                        (size_t)(half * 64 + ks * 32 + (lg << 3)) * 64 + ni * 16 + li;
                    bf16x8 bfr;
#pragma unroll
                    for (int j = 0; j < 8; ++j) bfr[j] = (short)f2b(Wp[(size_t)j * 64]);
                    acc[ni] = MFMA16(afr, bfr, acc[ni]);
                }
            }
            // transpose via wave-private sT, then coalesced dwordx4 stores
#pragma unroll
            for (int ni = 0; ni < 4; ++ni)
#pragma unroll
                for (int reg = 0; reg < 4; ++reg)
                    sT[w][lg * 4 + reg][ni * 16 + li] =
                        f2b(acc[ni][reg] + (half ? 0.f : be1v[ni]));
#pragma unroll
            for (int pass = 0; pass < 2; ++pass) {
                const int rr = pass * 8 + (lane >> 3);
                const int n = t * 64 + w * 16 + rr;
                const bf16x8 v = *(const bf16x8*)&sT[w][rr][(lane & 7) * 8];
                if (n < NN) *(bf16x8*)&out[(size_t)n * 64 + (lane & 7) * 8] = v;
            }
        }
    } else if (b < P1_COPY0) {
        float4* dst = (float4*)msg_agg;
        int i = (b - P1_ZERO0) * 256 + tid;
        for (; i < NN * 16; i += P1_ZERO * 256) dst[i] = make_float4(0.f, 0.f, 0.f, 0.f);
    } else {
        if (b == P1_COPY0 && tid < 128) gh[GHN + tid] = 0;  // scan aux (aggs+flags)
        int i = (b - P1_COPY0) * 256 + tid;
        for (; i < 37500 + NN; i += P1_COPY * 256) {
            if (i < 37500) {
                ((float4*)pos_out)[i] = ((const float4*)pos)[i];
            } else {
                const int n = i - 37500;
                pos4[n] = make_float4(pos[3 * n], pos[3 * n + 1], pos[3 * n + 2], 0.f);
            }
        }
    }
}

// ---------------- K2: 63-block one-pass scan with lane-parallel lookback ----------------
// aux[0..SCAN_NB) = aggregates, aux[SCAN_NB..2*SCAN_NB) = ready flags.
// <=63 single-lane waiters per flag: the verified regime.

__global__ __launch_bounds__(1024) void scan_kernel(int* __restrict__ cur,
                                                    int* __restrict__ aux) {
    __shared__ int wsum[16];
    __shared__ int s_prefix;
    const int b = blockIdx.x, t = threadIdx.x;
    const int g = b * 1024 + t;
    const int lane = t & 63, wid = t >> 6;
    const int v = (g < GHN) ? cur[g] : 0;
    int inc = v;
#pragma unroll
    for (int d = 1; d < 64; d <<= 1) {
        const int o = __shfl_up(inc, d, 64);
        if (lane >= d) inc += o;
    }
    if (lane == 63) wsum[wid] = inc;
    __syncthreads();
    if (t < 16) {
        int x = wsum[t];
#pragma unroll
        for (int d = 1; d < 16; d <<= 1) {
            const int o = __shfl_up(x, d, 16);
            if (t >= d) x += o;
        }
        wsum[t] = x;  // inclusive per-wave sums
    }
    __syncthreads();
    const int block_excl_w = (wid == 0) ? 0 : wsum[wid - 1];
    const int ex_in_block = block_excl_w + inc - v;
    if (t == 0) {
        __hip_atomic_store(&aux[b], wsum[15], __ATOMIC_RELAXED, __HIP_MEMORY_SCOPE_AGENT);
        __hip_atomic_store(&aux[SCAN_NB + b], 1, __ATOMIC_RELEASE, __HIP_MEMORY_SCOPE_AGENT);
    }
    if (t < 64) {
        int s = 0;
        if (t < b) {
            while (__hip_atomic_load(&aux[SCAN_NB + t], __ATOMIC_ACQUIRE,
                                     __HIP_MEMORY_SCOPE_AGENT) == 0) {
                __builtin_amdgcn_s_sleep(2);
            }
            s = __hip_atomic_load(&aux[t], __ATOMIC_RELAXED, __HIP_MEMORY_SCOPE_AGENT);
        }
#pragma unroll
        for (int m = 1; m < 64; m <<= 1) s += __shfl_xor(s, m, 64);
        if (t == 0) s_prefix = s;
    }
    __syncthreads();
    if (g < GHN) cur[g] = s_prefix + ex_in_block;
}

// ---------------- K3: scatter edges to coarse-bucket regions ----------------

__global__ __launch_bounds__(256) void scat_kernel(const int* __restrict__ ei,
                                                   const int* __restrict__ gh,
                                                   int2* __restrict__ sorted_rc) {
    __shared__ int off[256];
    const int b = blockIdx.x, t = threadIdx.x;
    off[t] = gh[t * SBLK + b];
    __syncthreads();
    const int base = b * SCHUNK;
    for (int i = base + t; i < base + SCHUNK; i += 256) {
        const int r = ei[i];
        const int c = ei[NE + i];
        const int p = atomicAdd(&off[r >> 8], 1);
        sorted_rc[p] = make_int2(r, c);
    }
}

// ---------------- K4: per-bucket counting sort (bin = row & 255) ----------------

__global__ __launch_bounds__(256) void bsort_kernel(const int* __restrict__ gh,
                                                    int2* __restrict__ sorted_rc) {
    __shared__ int h2[256];
    __shared__ int sc[256];
    __shared__ int off2[256];
    __shared__ __align__(16) int2 stage[4096];
    const int k = blockIdx.x, t = threadIdx.x;
    const int start = gh[k * SBLK];
    const int end   = gh[(k + 1) * SBLK];
    for (int cb = start; cb < end; cb += 4096) {
        const int cnt = min(4096, end - cb);
        h2[t] = 0;
        __syncthreads();
        int2 le[16];
        int nloc = 0;
#pragma unroll
        for (int jj = 0; jj < 16; ++jj) {
            const int j = jj * 256 + t;
            if (j < cnt) {
                const int2 e = sorted_rc[cb + j];
                le[jj] = e;
                atomicAdd(&h2[e.x & 255], 1);
                nloc = jj + 1;
            }
        }
        __syncthreads();
        sc[t] = h2[t];
        __syncthreads();
        for (int d = 1; d < 256; d <<= 1) {
            const int v = (t >= d) ? sc[t - d] : 0;
            __syncthreads();
            sc[t] += v;
            __syncthreads();
        }
        off2[t] = sc[t] - h2[t];   // exclusive prefix
        __syncthreads();
#pragma unroll
        for (int jj = 0; jj < 16; ++jj) {
            if (jj < nloc) {
                const int rank = atomicAdd(&off2[le[jj].x & 255], 1);
                stage[rank] = le[jj];
            }
        }
        __syncthreads();
        for (int j = t; j < cnt; j += 256) sorted_rc[cb + j] = stage[j];
        __syncthreads();
    }
}

// ---------------- K5: edge kernel (round-8/11 body, occupancy 8) ----------------

__global__ __launch_bounds__(256, 8) void egnn_edge_kernel(
    const float4* __restrict__ pos4, const int2* __restrict__ sorted_rc,
    const unsigned short* __restrict__ a1r, const unsigned short* __restrict__ a1c,
    const float* __restrict__ We1,  // row 128 = dist weights
    const unsigned short* __restrict__ wfrag,
    const float* __restrict__ be2, const float* __restrict__ bc1,
    const float* __restrict__ Wc2, const float* __restrict__ bc2,
    float* __restrict__ msg_agg, float* __restrict__ pos_out)
{
    __shared__ __align__(16) unsigned short sA[64][80];  // [edge][chan]
    __shared__ __align__(8) int2 srce[64];               // (row,col)
    __shared__ __align__(16) float4 sdr[64];             // (rx,ry,rz,dsq)
    __shared__ float scw[64];

    const int tid = threadIdx.x;
    const int lane = tid & 63, w = tid >> 6;
    const int li = lane & 15, lg = lane >> 4;
    const int tile = blockIdx.x;
    const int e0 = w * 16;

    // phase 0 (per wave, lanes 0-15): endpoints + relpos for own 16 edges
    if (lane < 16) {
        const int e = e0 + lane;
        const int2 rc = sorted_rc[tile * 64 + e];
        const float4 pr = pos4[rc.x];
        const float4 pc = pos4[rc.y];
        const float rx = pr.x - pc.x, ry = pr.y - pc.y, rz = pr.z - pc.z;
        srce[e] = rc;
        sdr[e] = make_float4(rx, ry, rz, rx * rx + ry * ry + rz * rz);
    }

    const int c8 = lane & 7;   // channel chunk
    const int eo = lane >> 3;  // edge offset within group of 8

    float w1d8[8];
    {
        const float* wd = We1 + 128 * 64 + c8 * 8;
        const float4 wa = *(const float4*)wd;
        const float4 wb = *(const float4*)(wd + 4);
        w1d8[0] = wa.x; w1d8[1] = wa.y; w1d8[2] = wa.z; w1d8[3] = wa.w;
        w1d8[4] = wb.x; w1d8[5] = wb.y; w1d8[6] = wb.z; w1d8[7] = wb.w;
    }
    float be2v[4], bc1v[4], wc2v[4];
#pragma unroll
    for (int ni = 0; ni < 4; ++ni) {
        be2v[ni] = be2[ni * 16 + li];
        bc1v[ni] = bc1[ni * 16 + li];
        wc2v[ni] = Wc2[ni * 16 + li];
    }
    const float bc2s = bc2[0];

    // phase 2: stage m for own 16 edges (same-wave LDS rows; no barrier needed)
#pragma unroll
    for (int hh = 0; hh < 2; ++hh) {
        const int e = e0 + hh * 8 + eo;
        const int2 rc = srce[e];
        const float dv = sdr[e].w;
        const bf16x8 ar = *(const bf16x8*)(a1r + (size_t)rc.x * 64 + c8 * 8);
        const bf16x8 ac = *(const bf16x8*)(a1c + (size_t)rc.y * 64 + c8 * 8);
        bf16x8 out;
#pragma unroll
        for (int j = 0; j < 8; ++j) {
            const float m = b2f((unsigned short)ar[j]) + b2f((unsigned short)ac[j])
                          + dv * w1d8[j];
            out[j] = (short)f2b(silu_f(m));
        }
        *(bf16x8*)&sA[e][c8 * 8] = out;
    }

    // phase 3: GEMM2 (msg_pre = m @ We2)
    f32x4 acc[4];
#pragma unroll
    for (int ni = 0; ni < 4; ++ni) acc[ni] = (f32x4)(0.0f);
#pragma unroll
    for (int ks = 0; ks < 2; ++ks) {
        const bf16x8 af = *(const bf16x8*)&sA[e0 + li][ks * 32 + (lg << 3)];
#pragma unroll
        for (int ni = 0; ni < 4; ++ni) {
            const bf16x8 bf = *(const bf16x8*)(wfrag + (size_t)(ks * 4 + ni) * 512 + lane * 8);
            acc[ni] = MFMA16(af, bf, acc[ni]);
        }
    }

    // phase 4: msg = silu(msg_pre + be2) -> sA (own rows)
#pragma unroll
    for (int ni = 0; ni < 4; ++ni)
#pragma unroll
        for (int reg = 0; reg < 4; ++reg)
            sA[e0 + lg * 4 + reg][ni * 16 + li] = f2b(silu_f(acc[ni][reg] + be2v[ni]));

    // phase 5: msg quarter-sweep (rows non-decreasing)
    {
        float macc = 0.0f;
        int pr = srce[e0].x;
#pragma unroll
        for (int j = 0; j < 16; ++j) {
            const int re = srce[e0 + j].x;
            if (re != pr) {
                atomicAdd(&msg_agg[(size_t)pr * 64 + lane], macc);
                macc = 0.0f;
                pr = re;
            }
            macc += b2f(sA[e0 + j][lane]);
        }
        atomicAdd(&msg_agg[(size_t)pr * 64 + lane], macc);
    }

    // phase 6: GEMM3 (t = msg @ Wc1)
    f32x4 a3[4];
#pragma unroll
    for (int ni = 0; ni < 4; ++ni) a3[ni] = (f32x4)(0.0f);
#pragma unroll
    for (int ks = 0; ks < 2; ++ks) {
        const bf16x8 af = *(const bf16x8*)&sA[e0 + li][ks * 32 + (lg << 3)];
#pragma unroll
        for (int ni = 0; ni < 4; ++ni) {
            const bf16x8 bf = *(const bf16x8*)(wfrag + (size_t)(8 + ks * 4 + ni) * 512 + lane * 8);
            a3[ni] = MFMA16(af, bf, a3[ni]);
        }
    }

    // epilogue: cw[edge] = sum_c silu(t+bc1)[c] * Wc2[c]
    float sv[4];
#pragma unroll
    for (int reg = 0; reg < 4; ++reg) {
        float s = 0.0f;
#pragma unroll
        for (int ni = 0; ni < 4; ++ni)
            s += silu_f(a3[ni][reg] + bc1v[ni]) * wc2v[ni];
        sv[reg] = s;
    }
#pragma unroll
    for (int m = 1; m < 16; m <<= 1)
#pragma unroll
        for (int reg = 0; reg < 4; ++reg) sv[reg] += __shfl_xor(sv[reg], m, 64);
    if (li == 0) {
        float4 cv = make_float4(sv[0] + bc2s, sv[1] + bc2s, sv[2] + bc2s, sv[3] + bc2s);
        *(float4*)&scw[e0 + lg * 4] = cv;
    }
    __syncthreads();  // the only block barrier: publishes srce/sdr/scw to wave 0

    // phase 7: coord aggregation (wave 0): segmented scan, 1 atomic triplet/run
    if (tid < 64) {
        const float4 dr = sdr[tid];
        const int r_e = srce[tid].x;
        const float cw = scw[tid];
        float vx = dr.x * cw, vy = dr.y * cw, vz = dr.z * cw;
#pragma unroll
        for (int d = 1; d < 64; d <<= 1) {
            const float ox = __shfl_up(vx, d, 64);
            const float oy = __shfl_up(vy, d, 64);
            const float oz = __shfl_up(vz, d, 64);
            const int   orr = __shfl_up(r_e, d, 64);
            const bool add = (tid >= d) && (orr == r_e);
            vx += add ? ox : 0.0f;
            vy += add ? oy : 0.0f;
            vz += add ? oz : 0.0f;
        }
        const int rnext = __shfl_down(r_e, 1, 64);
        const bool last = (tid == 63) || (rnext != r_e);
        if (last) {
            atomicAdd(&pos_out[r_e * 3 + 0], vx);
            atomicAdd(&pos_out[r_e * 3 + 1], vy);
            atomicAdd(&pos_out[r_e * 3 + 2], vz);
        }
    }
}

// ---------------- K6: node MLP (one 64-node tile per block) ----------------

__global__ __launch_bounds__(256, 4) void node_kernel(
    const float* __restrict__ h, const float* __restrict__ msg_agg,
    const unsigned short* __restrict__ wfrag,
    const float* __restrict__ bn1, const float* __restrict__ bn2,
    float* __restrict__ h_out)
{
    __shared__ __align__(16) unsigned short sA[64][136];
    const int tid = threadIdx.x;
    const int lane = tid & 63, w = tid >> 6;
    const int t = blockIdx.x;
    const int li = lane & 15, lg = lane >> 4;

    float bn1v[4], bn2v[4];
#pragma unroll
    for (int ni = 0; ni < 4; ++ni) {
        bn1v[ni] = bn1[ni * 16 + li];
        bn2v[ni] = bn2[ni * 16 + li];
    }

    // stage own 16 rows of [h | msg] (K=128): cols 0-63 h, 64-127 msg
#pragma unroll
    for (int pass = 0; pass < 8; ++pass) {
        const int idx = pass * 64 + lane;          // 0..511
        const int n_loc = w * 16 + (idx >> 5);     // own rows
        const int c4 = idx & 31;                   // float4 chunk 0..31
        const int n = t * 64 + n_loc;
        float4 v = make_float4(0.f, 0.f, 0.f, 0.f);
        if (n < NN) {
            const float* src = (c4 < 16) ? &h[(size_t)n * 64 + c4 * 4]
                                         : &msg_agg[(size_t)n * 64 + (c4 - 16) * 4];
            v = *(const float4*)src;
        }
        bf16x4 p;
        p[0] = (short)f2b(v.x); p[1] = (short)f2b(v.y);
        p[2] = (short)f2b(v.z); p[3] = (short)f2b(v.w);
        *(bf16x4*)&sA[n_loc][c4 * 4] = p;
    }

    // GEMM1: K=128
    f32x4 acc[4];
#pragma unroll
    for (int ni = 0; ni < 4; ++ni) acc[ni] = (f32x4)(0.0f);
#pragma unroll
    for (int ks = 0; ks < 4; ++ks) {
        const bf16x8 afr = *(const bf16x8*)&sA[w * 16 + li][ks * 32 + (lg << 3)];
#pragma unroll
        for (int ni = 0; ni < 4; ++ni) {
            const bf16x8 bfr = *(const bf16x8*)(wfrag + (size_t)(16 + ks * 4 + ni) * 512 + lane * 8);
            acc[ni] = MFMA16(afr, bfr, acc[ni]);
        }
    }
    // silu + bn1 -> sA cols 0..63 (own rows)
#pragma unroll
    for (int ni = 0; ni < 4; ++ni)
#pragma unroll
        for (int reg = 0; reg < 4; ++reg)
            sA[w * 16 + lg * 4 + reg][ni * 16 + li] = f2b(silu_f(acc[ni][reg] + bn1v[ni]));

    // GEMM2: K=64
    f32x4 a2[4];
#pragma unroll
    for (int ni = 0; ni < 4; ++ni) a2[ni] = (f32x4)(0.0f);
#pragma unroll
    for (int ks = 0; ks < 2; ++ks) {
        const bf16x8 afr = *(const bf16x8*)&sA[w * 16 + li][ks * 32 + (lg << 3)];
#pragma unroll
        for (int ni = 0; ni < 4; ++ni) {
            const bf16x8 bfr = *(const bf16x8*)(wfrag + (size_t)(32 + ks * 4 + ni) * 512 + lane * 8);
            a2[ni] = MFMA16(afr, bfr, a2[ni]);
        }
    }
#pragma unroll
    for (int ni = 0; ni < 4; ++ni)
#pragma unroll
        for (int reg = 0; reg < 4; ++reg) {
            const int n = t * 64 + w * 16 + lg * 4 + reg;
            if (n < NN) h_out[(size_t)n * 64 + ni * 16 + li] = a2[ni][reg] + bn2v[ni];
        }
}

// ---------------- launch ----------------

extern "C" void kernel_launch(void* const* d_in, const int* in_sizes, int n_in,
                              void* d_out, int out_size, void* d_ws, size_t ws_size,
                              hipStream_t stream) {
    const float* h   = (const float*)d_in[0];
    const float* pos = (const float*)d_in[1];
    const int*   ei  = (const int*)d_in[2];
    const float* We1 = (const float*)d_in[3];
    const float* be1 = (const float*)d_in[4];
    const float* We2 = (const float*)d_in[5];
    const float* be2 = (const float*)d_in[6];
    const float* Wc1 = (const float*)d_in[7];
    const float* bc1 = (const float*)d_in[8];
    const float* Wc2 = (const float*)d_in[9];
    const float* bc2 = (const float*)d_in[10];
    const float* Wn1 = (const float*)d_in[11];
    const float* bn1 = (const float*)d_in[12];
    const float* Wn2 = (const float*)d_in[13];
    const float* bn2 = (const float*)d_in[14];

    unsigned short* a1r   = (unsigned short*)d_ws;            // [N*64] bf16
    unsigned short* a1c   = a1r + (size_t)NN * 64;            // [N*64] bf16
    unsigned short* wfrag = a1c + (size_t)NN * 64;            // 40 frags * 512
    int2* sorted_rc = (int2*)(wfrag + 40 * 512);              // [E]
    int*  gh        = (int*)(sorted_rc + NE);                 // 64000 + 128 aux
    float4* pos4    = (float4*)(gh + GHN + 128);              // [N]

    float* msg_agg = (float*)d_out;                           // reused as h_out
    float* pos_out = msg_agg + (size_t)NN * 64;

    prep_kernel<<<K1_GRID, 256, 0, stream>>>(h, pos, be1, We1, We2, Wc1, Wn1, Wn2,
                                             ei, wfrag, gh, a1r, a1c,
                                             msg_agg, pos_out, pos4);
    scan_kernel<<<SCAN_NB, 1024, 0, stream>>>(gh, gh + GHN);
    scat_kernel<<<SBLK, 256, 0, stream>>>(ei, gh, sorted_rc);
    bsort_kernel<<<NBUK, 256, 0, stream>>>(gh, sorted_rc);
    egnn_edge_kernel<<<ETILE, 256, 0, stream>>>(pos4, sorted_rc, a1r, a1c, We1, wfrag,
                                                be2, bc1, Wc2, bc2, msg_agg, pos_out);
    node_kernel<<<782, 256, 0, stream>>>(h, msg_agg, wfrag, bn1, bn2, msg_agg);
}

// Round 18
// 198.479 us; speedup vs baseline: 2.0223x; 1.0059x over previous
//
#include <hip/hip_runtime.h>

// EGNN conv: N=50000, E=800000, C=64.
// Round 25 == round 21 resubmitted (rounds 14/15/16/17 bench slots all hit
// GPUAcquisitionTimeouts; the cvt_pk edge kernel has never been measured).
// Round-20 measured edge 66.4us @ VALUBusy 85% / occ 72% (occupancy bump done;
// VALU op count is now the limiter). This build replaces 2-op f2b bit-twiddle
// packs with 1-op-per-pair v_cvt_pk_bf16_f32 (inline asm) in edge phases 2 and
// 4: ~-40 VALU ops/lane (~11%). RNE vs round-half-up: +-1ulp bf16, same error
// class. ALL OTHER KERNELS byte-identical to the measured 199.6us round-20
// build for clean attribution.
// Lessons ledger: mass-spin on one flag = fabric poison (85us @ 0.3% VALU);
// big-LDS spin fusion idles CUs; device-scope atomic storms ~1.5TB/s fabric.

#define NN 50000
#define NE 800000
#define ETILE 12500         // NE/64

// sort geometry
#define SBLK 250            // passA/scat blocks
#define SCHUNK 3200         // NE/SBLK edges per block
#define NBUK 196            // buckets = ceil(50000/256)
#define GHN 64000           // 256*SBLK counters
#define SCAN_NB 63          // 63*1024 >= 64000

typedef __attribute__((ext_vector_type(8))) short bf16x8;
typedef __attribute__((ext_vector_type(4))) short bf16x4;
typedef __attribute__((ext_vector_type(4))) float f32x4;

#define MFMA16(a, b, c) __builtin_amdgcn_mfma_f32_16x16x32_bf16(a, b, c, 0, 0, 0)

__device__ __forceinline__ unsigned short f2b(float x) {
    union { float f; unsigned u; } v; v.f = x;
    return (unsigned short)((v.u + 0x8000u) >> 16);
}
__device__ __forceinline__ float b2f(unsigned short b) {
    union { unsigned u; float f; } v; v.u = ((unsigned)b) << 16; return v.f;
}
__device__ __forceinline__ float silu_f(float x) {
    return x * __builtin_amdgcn_rcpf(1.0f + __expf(-x));
}
// pack 2 floats -> 2 bf16 (RNE) in ONE VALU op (no builtin on gfx950; T12)
__device__ __forceinline__ unsigned pk2(float lo, float hi) {
    unsigned r;
    asm("v_cvt_pk_bf16_f32 %0, %1, %2" : "=v"(r) : "v"(lo), "v"(hi));
    return r;
}

// wfrag layout (40 frags x 512 bf16): 0..7 We2, 8..15 Wc1, 16..31 Wn1,
// 32..39 Wn2. node_pre loads We1 directly from global (L2-resident).

// ---------------- K1: passA || frag || node_pre || zero || copy ----------------

#define P1_A 250
#define P1_FRAG 10
#define P1_NPRE 782
#define P1_ZERO 200
#define P1_COPY 16
#define P1_FRAG0 (P1_A)
#define P1_NPRE0 (P1_A + P1_FRAG)
#define P1_ZERO0 (P1_NPRE0 + P1_NPRE)
#define P1_COPY0 (P1_ZERO0 + P1_ZERO)
#define K1_GRID (P1_COPY0 + P1_COPY)

__global__ __launch_bounds__(256, 4) void prep_kernel(
    const float* __restrict__ h, const float* __restrict__ pos,
    const float* __restrict__ be1,
    const float* __restrict__ We1, const float* __restrict__ We2,
    const float* __restrict__ Wc1, const float* __restrict__ Wn1,
    const float* __restrict__ Wn2, const int* __restrict__ ei,
    unsigned short* __restrict__ wfrag, int* __restrict__ gh,
    unsigned short* __restrict__ a1r, unsigned short* __restrict__ a1c,
    float* __restrict__ msg_agg, float* __restrict__ pos_out,
    float4* __restrict__ pos4)
{
    __shared__ __align__(16) unsigned short sH[64][72];
    __shared__ __align__(16) unsigned short sT[4][16][72];
    __shared__ int lh[256];
    const int b = blockIdx.x, tid = threadIdx.x;
    if (b < P1_A) {
        // coarse bucket histogram for this block's 3200 edges
        lh[tid] = 0;
        __syncthreads();
        const int base = b * SCHUNK;
        for (int i = base + tid; i < base + SCHUNK; i += 256)
            atomicAdd(&lh[ei[i] >> 8], 1);
        __syncthreads();
        gh[tid * SBLK + b] = lh[tid];   // bucket-major [256][SBLK]
    } else if (b < P1_NPRE0) {
        const int lane = tid & 63, w = tid >> 6;
        const int li = lane & 15, lg = lane >> 4;
        const int f = (b - P1_FRAG0) * 4 + w;  // 0..39
        const float* W; int g;
        if (f < 8)       { W = We2; g = f; }
        else if (f < 16) { W = Wc1; g = f - 8; }
        else if (f < 32) { W = Wn1; g = f - 16; }
        else             { W = Wn2; g = f - 32; }
        const int ks = g >> 2, ni = g & 3;
        const int n = ni * 16 + li, kb = ks * 32 + (lg << 3);
        bf16x8 v;
#pragma unroll
        for (int j = 0; j < 8; ++j) v[j] = (short)f2b(W[(kb + j) * 64 + n]);
        *(bf16x8*)(wfrag + (size_t)f * 512 + lane * 8) = v;
    } else if (b < P1_ZERO0) {
        // node_pre: one 64-node tile per block; wave w owns rows [w*16, w*16+16)
        const int lane = tid & 63, w = tid >> 6;
        const int li = lane & 15, lg = lane >> 4;
        const int t = b - P1_NPRE0;
        const int c4 = lane & 15, rsub = lane >> 4;
#pragma unroll
        for (int pass = 0; pass < 4; ++pass) {
            const int n_loc = w * 16 + pass * 4 + rsub;
            const int n = t * 64 + n_loc;
            float4 hv = make_float4(0.f, 0.f, 0.f, 0.f);
            if (n < NN) hv = *(const float4*)&h[(size_t)n * 64 + c4 * 4];
            bf16x4 hp;
            hp[0] = (short)f2b(hv.x); hp[1] = (short)f2b(hv.y);
            hp[2] = (short)f2b(hv.z); hp[3] = (short)f2b(hv.w);
            *(bf16x4*)&sH[n_loc][c4 * 4] = hp;   // wave-private rows
        }
        float be1v[4];
#pragma unroll
        for (int ni = 0; ni < 4; ++ni) be1v[ni] = be1[ni * 16 + li];

#pragma unroll
        for (int half = 0; half < 2; ++half) {
            unsigned short* out = half ? a1c : a1r;
            f32x4 acc[4];
#pragma unroll
            for (int ni = 0; ni < 4; ++ni) acc[ni] = (f32x4)(0.0f);
#pragma unroll
            for (int ks = 0; ks < 2; ++ks) {
                const bf16x8 afr = *(const bf16x8*)&sH[w * 16 + li][ks * 32 + (lg << 3)];
#pragma unroll
                for (int ni = 0; ni < 4; ++ni) {
                    // We1 B-fragment direct from global (L2-resident):
                    const float* Wp = We1 +
                        (size_t)(half * 64 + ks * 32 + (lg << 3)) * 64 + ni * 16 + li;
                    bf16x8 bfr;
#pragma unroll
                    for (int j = 0; j < 8; ++j) bfr[j] = (short)f2b(Wp[(size_t)j * 64]);
                    acc[ni] = MFMA16(afr, bfr, acc[ni]);
                }
            }
            // transpose via wave-private sT, then coalesced dwordx4 stores
#pragma unroll
            for (int ni = 0; ni < 4; ++ni)
#pragma unroll
                for (int reg = 0; reg < 4; ++reg)
                    sT[w][lg * 4 + reg][ni * 16 + li] =
                        f2b(acc[ni][reg] + (half ? 0.f : be1v[ni]));
#pragma unroll
            for (int pass = 0; pass < 2; ++pass) {
                const int rr = pass * 8 + (lane >> 3);
                const int n = t * 64 + w * 16 + rr;
                const bf16x8 v = *(const bf16x8*)&sT[w][rr][(lane & 7) * 8];
                if (n < NN) *(bf16x8*)&out[(size_t)n * 64 + (lane & 7) * 8] = v;
            }
        }
    } else if (b < P1_COPY0) {
        float4* dst = (float4*)msg_agg;
        int i = (b - P1_ZERO0) * 256 + tid;
        for (; i < NN * 16; i += P1_ZERO * 256) dst[i] = make_float4(0.f, 0.f, 0.f, 0.f);
    } else {
        if (b == P1_COPY0 && tid < 128) gh[GHN + tid] = 0;  // scan aux (aggs+flags)
        int i = (b - P1_COPY0) * 256 + tid;
        for (; i < 37500 + NN; i += P1_COPY * 256) {
            if (i < 37500) {
                ((float4*)pos_out)[i] = ((const float4*)pos)[i];
            } else {
                const int n = i - 37500;
                pos4[n] = make_float4(pos[3 * n], pos[3 * n + 1], pos[3 * n + 2], 0.f);
            }
        }
    }
}

// ---------------- K2: 63-block one-pass scan with lane-parallel lookback ----------------
// aux[0..SCAN_NB) = aggregates, aux[SCAN_NB..2*SCAN_NB) = ready flags.
// <=63 single-lane waiters per flag: the verified regime.

__global__ __launch_bounds__(1024) void scan_kernel(int* __restrict__ cur,
                                                    int* __restrict__ aux) {
    __shared__ int wsum[16];
    __shared__ int s_prefix;
    const int b = blockIdx.x, t = threadIdx.x;
    const int g = b * 1024 + t;
    const int lane = t & 63, wid = t >> 6;
    const int v = (g < GHN) ? cur[g] : 0;
    int inc = v;
#pragma unroll
    for (int d = 1; d < 64; d <<= 1) {
        const int o = __shfl_up(inc, d, 64);
        if (lane >= d) inc += o;
    }
    if (lane == 63) wsum[wid] = inc;
    __syncthreads();
    if (t < 16) {
        int x = wsum[t];
#pragma unroll
        for (int d = 1; d < 16; d <<= 1) {
            const int o = __shfl_up(x, d, 16);
            if (t >= d) x += o;
        }
        wsum[t] = x;  // inclusive per-wave sums
    }
    __syncthreads();
    const int block_excl_w = (wid == 0) ? 0 : wsum[wid - 1];
    const int ex_in_block = block_excl_w + inc - v;
    if (t == 0) {
        __hip_atomic_store(&aux[b], wsum[15], __ATOMIC_RELAXED, __HIP_MEMORY_SCOPE_AGENT);
        __hip_atomic_store(&aux[SCAN_NB + b], 1, __ATOMIC_RELEASE, __HIP_MEMORY_SCOPE_AGENT);
    }
    if (t < 64) {
        int s = 0;
        if (t < b) {
            while (__hip_atomic_load(&aux[SCAN_NB + t], __ATOMIC_ACQUIRE,
                                     __HIP_MEMORY_SCOPE_AGENT) == 0) {
                __builtin_amdgcn_s_sleep(2);
            }
            s = __hip_atomic_load(&aux[t], __ATOMIC_RELAXED, __HIP_MEMORY_SCOPE_AGENT);
        }
#pragma unroll
        for (int m = 1; m < 64; m <<= 1) s += __shfl_xor(s, m, 64);
        if (t == 0) s_prefix = s;
    }
    __syncthreads();
    if (g < GHN) cur[g] = s_prefix + ex_in_block;
}

// ---------------- K3: scatter edges to coarse-bucket regions ----------------

__global__ __launch_bounds__(256) void scat_kernel(const int* __restrict__ ei,
                                                   const int* __restrict__ gh,
                                                   int2* __restrict__ sorted_rc) {
    __shared__ int off[256];
    const int b = blockIdx.x, t = threadIdx.x;
    off[t] = gh[t * SBLK + b];
    __syncthreads();
    const int base = b * SCHUNK;
    for (int i = base + t; i < base + SCHUNK; i += 256) {
        const int r = ei[i];
        const int c = ei[NE + i];
        const int p = atomicAdd(&off[r >> 8], 1);
        sorted_rc[p] = make_int2(r, c);
    }
}

// ---------------- K4: per-bucket counting sort (bin = row & 255) ----------------

__global__ __launch_bounds__(256) void bsort_kernel(const int* __restrict__ gh,
                                                    int2* __restrict__ sorted_rc) {
    __shared__ int h2[256];
    __shared__ int sc[256];
    __shared__ int off2[256];
    __shared__ __align__(16) int2 stage[4096];
    const int k = blockIdx.x, t = threadIdx.x;
    const int start = gh[k * SBLK];
    const int end   = gh[(k + 1) * SBLK];
    for (int cb = start; cb < end; cb += 4096) {
        const int cnt = min(4096, end - cb);
        h2[t] = 0;
        __syncthreads();
        int2 le[16];
        int nloc = 0;
#pragma unroll
        for (int jj = 0; jj < 16; ++jj) {
            const int j = jj * 256 + t;
            if (j < cnt) {
                const int2 e = sorted_rc[cb + j];
                le[jj] = e;
                atomicAdd(&h2[e.x & 255], 1);
                nloc = jj + 1;
            }
        }
        __syncthreads();
        sc[t] = h2[t];
        __syncthreads();
        for (int d = 1; d < 256; d <<= 1) {
            const int v = (t >= d) ? sc[t - d] : 0;
            __syncthreads();
            sc[t] += v;
            __syncthreads();
        }
        off2[t] = sc[t] - h2[t];   // exclusive prefix
        __syncthreads();
#pragma unroll
        for (int jj = 0; jj < 16; ++jj) {
            if (jj < nloc) {
                const int rank = atomicAdd(&off2[le[jj].x & 255], 1);
                stage[rank] = le[jj];
            }
        }
        __syncthreads();
        for (int j = t; j < cnt; j += 256) sorted_rc[cb + j] = stage[j];
        __syncthreads();
    }
}

// ---------------- K5: edge kernel (occupancy 8; cvt_pk bf16 packing) ----------------

__global__ __launch_bounds__(256, 8) void egnn_edge_kernel(
    const float4* __restrict__ pos4, const int2* __restrict__ sorted_rc,
    const unsigned short* __restrict__ a1r, const unsigned short* __restrict__ a1c,
    const float* __restrict__ We1,  // row 128 = dist weights
    const unsigned short* __restrict__ wfrag,
    const float* __restrict__ be2, const float* __restrict__ bc1,
    const float* __restrict__ Wc2, const float* __restrict__ bc2,
    float* __restrict__ msg_agg, float* __restrict__ pos_out)
{
    __shared__ __align__(16) unsigned short sA[64][80];  // [edge][chan]
    __shared__ __align__(8) int2 srce[64];               // (row,col)
    __shared__ __align__(16) float4 sdr[64];             // (rx,ry,rz,dsq)
    __shared__ float scw[64];

    const int tid = threadIdx.x;
    const int lane = tid & 63, w = tid >> 6;
    const int li = lane & 15, lg = lane >> 4;
    const int tile = blockIdx.x;
    const int e0 = w * 16;

    // phase 0 (per wave, lanes 0-15): endpoints + relpos for own 16 edges
    if (lane < 16) {
        const int e = e0 + lane;
        const int2 rc = sorted_rc[tile * 64 + e];
        const float4 pr = pos4[rc.x];
        const float4 pc = pos4[rc.y];
        const float rx = pr.x - pc.x, ry = pr.y - pc.y, rz = pr.z - pc.z;
        srce[e] = rc;
        sdr[e] = make_float4(rx, ry, rz, rx * rx + ry * ry + rz * rz);
    }

    const int c8 = lane & 7;   // channel chunk
    const int eo = lane >> 3;  // edge offset within group of 8

    float w1d8[8];
    {
        const float* wd = We1 + 128 * 64 + c8 * 8;
        const float4 wa = *(const float4*)wd;
        const float4 wb = *(const float4*)(wd + 4);
        w1d8[0] = wa.x; w1d8[1] = wa.y; w1d8[2] = wa.z; w1d8[3] = wa.w;
        w1d8[4] = wb.x; w1d8[5] = wb.y; w1d8[6] = wb.z; w1d8[7] = wb.w;
    }
    float be2v[4], bc1v[4], wc2v[4];
#pragma unroll
    for (int ni = 0; ni < 4; ++ni) {
        be2v[ni] = be2[ni * 16 + li];
        bc1v[ni] = bc1[ni * 16 + li];
        wc2v[ni] = Wc2[ni * 16 + li];
    }
    const float bc2s = bc2[0];

    // phase 2: stage m for own 16 edges; pack pairs with v_cvt_pk_bf16_f32
#pragma unroll
    for (int hh = 0; hh < 2; ++hh) {
        const int e = e0 + hh * 8 + eo;
        const int2 rc = srce[e];
        const float dv = sdr[e].w;
        const bf16x8 ar = *(const bf16x8*)(a1r + (size_t)rc.x * 64 + c8 * 8);
        const bf16x8 ac = *(const bf16x8*)(a1c + (size_t)rc.y * 64 + c8 * 8);
        float s[8];
#pragma unroll
        for (int j = 0; j < 8; ++j) {
            const float m = b2f((unsigned short)ar[j]) + b2f((unsigned short)ac[j])
                          + dv * w1d8[j];
            s[j] = silu_f(m);
        }
        unsigned outp[4];
#pragma unroll
        for (int j = 0; j < 4; ++j) outp[j] = pk2(s[2 * j], s[2 * j + 1]);
        bf16x8 out;
        __builtin_memcpy(&out, outp, 16);
        *(bf16x8*)&sA[e][c8 * 8] = out;
    }

    // phase 3: GEMM2 (msg_pre = m @ We2)
    f32x4 acc[4];
#pragma unroll
    for (int ni = 0; ni < 4; ++ni) acc[ni] = (f32x4)(0.0f);
#pragma unroll
    for (int ks = 0; ks < 2; ++ks) {
        const bf16x8 af = *(const bf16x8*)&sA[e0 + li][ks * 32 + (lg << 3)];
#pragma unroll
        for (int ni = 0; ni < 4; ++ni) {
            const bf16x8 bf = *(const bf16x8*)(wfrag + (size_t)(ks * 4 + ni) * 512 + lane * 8);
            acc[ni] = MFMA16(af, bf, acc[ni]);
        }
    }

    // phase 4: msg = silu(msg_pre + be2) -> sA (own rows); pk2 per reg-pair
#pragma unroll
    for (int ni = 0; ni < 4; ++ni)
#pragma unroll
        for (int rp = 0; rp < 2; ++rp) {
            const unsigned p = pk2(silu_f(acc[ni][2 * rp] + be2v[ni]),
                                   silu_f(acc[ni][2 * rp + 1] + be2v[ni]));
            sA[e0 + lg * 4 + 2 * rp][ni * 16 + li] = (unsigned short)p;
            sA[e0 + lg * 4 + 2 * rp + 1][ni * 16 + li] = (unsigned short)(p >> 16);
        }

    // phase 5: msg quarter-sweep (rows non-decreasing)
    {
        float macc = 0.0f;
        int pr = srce[e0].x;
#pragma unroll
        for (int j = 0; j < 16; ++j) {
            const int re = srce[e0 + j].x;
            if (re != pr) {
                atomicAdd(&msg_agg[(size_t)pr * 64 + lane], macc);
                macc = 0.0f;
                pr = re;
            }
            macc += b2f(sA[e0 + j][lane]);
        }
        atomicAdd(&msg_agg[(size_t)pr * 64 + lane], macc);
    }

    // phase 6: GEMM3 (t = msg @ Wc1)
    f32x4 a3[4];
#pragma unroll
    for (int ni = 0; ni < 4; ++ni) a3[ni] = (f32x4)(0.0f);
#pragma unroll
    for (int ks = 0; ks < 2; ++ks) {
        const bf16x8 af = *(const bf16x8*)&sA[e0 + li][ks * 32 + (lg << 3)];
#pragma unroll
        for (int ni = 0; ni < 4; ++ni) {
            const bf16x8 bf = *(const bf16x8*)(wfrag + (size_t)(8 + ks * 4 + ni) * 512 + lane * 8);
            a3[ni] = MFMA16(af, bf, a3[ni]);
        }
    }

    // epilogue: cw[edge] = sum_c silu(t+bc1)[c] * Wc2[c]
    float sv[4];
#pragma unroll
    for (int reg = 0; reg < 4; ++reg) {
        float s = 0.0f;
#pragma unroll
        for (int ni = 0; ni < 4; ++ni)
            s += silu_f(a3[ni][reg] + bc1v[ni]) * wc2v[ni];
        sv[reg] = s;
    }
#pragma unroll
    for (int m = 1; m < 16; m <<= 1)
#pragma unroll
        for (int reg = 0; reg < 4; ++reg) sv[reg] += __shfl_xor(sv[reg], m, 64);
    if (li == 0) {
        float4 cv = make_float4(sv[0] + bc2s, sv[1] + bc2s, sv[2] + bc2s, sv[3] + bc2s);
        *(float4*)&scw[e0 + lg * 4] = cv;
    }
    __syncthreads();  // the only block barrier: publishes srce/sdr/scw to wave 0

    // phase 7: coord aggregation (wave 0): segmented scan, 1 atomic triplet/run
    if (tid < 64) {
        const float4 dr = sdr[tid];
        const int r_e = srce[tid].x;
        const float cw = scw[tid];
        float vx = dr.x * cw, vy = dr.y * cw, vz = dr.z * cw;
#pragma unroll
        for (int d = 1; d < 64; d <<= 1) {
            const float ox = __shfl_up(vx, d, 64);
            const float oy = __shfl_up(vy, d, 64);
            const float oz = __shfl_up(vz, d, 64);
            const int   orr = __shfl_up(r_e, d, 64);
            const bool add = (tid >= d) && (orr == r_e);
            vx += add ? ox : 0.0f;
            vy += add ? oy : 0.0f;
            vz += add ? oz : 0.0f;
        }
        const int rnext = __shfl_down(r_e, 1, 64);
        const bool last = (tid == 63) || (rnext != r_e);
        if (last) {
            atomicAdd(&pos_out[r_e * 3 + 0], vx);
            atomicAdd(&pos_out[r_e * 3 + 1], vy);
            atomicAdd(&pos_out[r_e * 3 + 2], vz);
        }
    }
}

// ---------------- K6: node MLP (one 64-node tile per block) ----------------

__global__ __launch_bounds__(256, 4) void node_kernel(
    const float* __restrict__ h, const float* __restrict__ msg_agg,
    const unsigned short* __restrict__ wfrag,
    const float* __restrict__ bn1, const float* __restrict__ bn2,
    float* __restrict__ h_out)
{
    __shared__ __align__(16) unsigned short sA[64][136];
    const int tid = threadIdx.x;
    const int lane = tid & 63, w = tid >> 6;
    const int t = blockIdx.x;
    const int li = lane & 15, lg = lane >> 4;

    float bn1v[4], bn2v[4];
#pragma unroll
    for (int ni = 0; ni < 4; ++ni) {
        bn1v[ni] = bn1[ni * 16 + li];
        bn2v[ni] = bn2[ni * 16 + li];
    }

    // stage own 16 rows of [h | msg] (K=128): cols 0-63 h, 64-127 msg
#pragma unroll
    for (int pass = 0; pass < 8; ++pass) {
        const int idx = pass * 64 + lane;          // 0..511
        const int n_loc = w * 16 + (idx >> 5);     // own rows
        const int c4 = idx & 31;                   // float4 chunk 0..31
        const int n = t * 64 + n_loc;
        float4 v = make_float4(0.f, 0.f, 0.f, 0.f);
        if (n < NN) {
            const float* src = (c4 < 16) ? &h[(size_t)n * 64 + c4 * 4]
                                         : &msg_agg[(size_t)n * 64 + (c4 - 16) * 4];
            v = *(const float4*)src;
        }
        bf16x4 p;
        p[0] = (short)f2b(v.x); p[1] = (short)f2b(v.y);
        p[2] = (short)f2b(v.z); p[3] = (short)f2b(v.w);
        *(bf16x4*)&sA[n_loc][c4 * 4] = p;
    }

    // GEMM1: K=128
    f32x4 acc[4];
#pragma unroll
    for (int ni = 0; ni < 4; ++ni) acc[ni] = (f32x4)(0.0f);
#pragma unroll
    for (int ks = 0; ks < 4; ++ks) {
        const bf16x8 afr = *(const bf16x8*)&sA[w * 16 + li][ks * 32 + (lg << 3)];
#pragma unroll
        for (int ni = 0; ni < 4; ++ni) {
            const bf16x8 bfr = *(const bf16x8*)(wfrag + (size_t)(16 + ks * 4 + ni) * 512 + lane * 8);
            acc[ni] = MFMA16(afr, bfr, acc[ni]);
        }
    }
    // silu + bn1 -> sA cols 0..63 (own rows)
#pragma unroll
    for (int ni = 0; ni < 4; ++ni)
#pragma unroll
        for (int reg = 0; reg < 4; ++reg)
            sA[w * 16 + lg * 4 + reg][ni * 16 + li] = f2b(silu_f(acc[ni][reg] + bn1v[ni]));

    // GEMM2: K=64
    f32x4 a2[4];
#pragma unroll
    for (int ni = 0; ni < 4; ++ni) a2[ni] = (f32x4)(0.0f);
#pragma unroll
    for (int ks = 0; ks < 2; ++ks) {
        const bf16x8 afr = *(const bf16x8*)&sA[w * 16 + li][ks * 32 + (lg << 3)];
#pragma unroll
        for (int ni = 0; ni < 4; ++ni) {
            const bf16x8 bfr = *(const bf16x8*)(wfrag + (size_t)(32 + ks * 4 + ni) * 512 + lane * 8);
            a2[ni] = MFMA16(afr, bfr, a2[ni]);
        }
    }
#pragma unroll
    for (int ni = 0; ni < 4; ++ni)
#pragma unroll
        for (int reg = 0; reg < 4; ++reg) {
            const int n = t * 64 + w * 16 + lg * 4 + reg;
            if (n < NN) h_out[(size_t)n * 64 + ni * 16 + li] = a2[ni][reg] + bn2v[ni];
        }
}

// ---------------- launch ----------------

extern "C" void kernel_launch(void* const* d_in, const int* in_sizes, int n_in,
                              void* d_out, int out_size, void* d_ws, size_t ws_size,
                              hipStream_t stream) {
    const float* h   = (const float*)d_in[0];
    const float* pos = (const float*)d_in[1];
    const int*   ei  = (const int*)d_in[2];
    const float* We1 = (const float*)d_in[3];
    const float* be1 = (const float*)d_in[4];
    const float* We2 = (const float*)d_in[5];
    const float* be2 = (const float*)d_in[6];
    const float* Wc1 = (const float*)d_in[7];
    const float* bc1 = (const float*)d_in[8];
    const float* Wc2 = (const float*)d_in[9];
    const float* bc2 = (const float*)d_in[10];
    const float* Wn1 = (const float*)d_in[11];
    const float* bn1 = (const float*)d_in[12];
    const float* Wn2 = (const float*)d_in[13];
    const float* bn2 = (const float*)d_in[14];

    unsigned short* a1r   = (unsigned short*)d_ws;            // [N*64] bf16
    unsigned short* a1c   = a1r + (size_t)NN * 64;            // [N*64] bf16
    unsigned short* wfrag = a1c + (size_t)NN * 64;            // 40 frags * 512
    int2* sorted_rc = (int2*)(wfrag + 40 * 512);              // [E]
    int*  gh        = (int*)(sorted_rc + NE);                 // 64000 + 128 aux
    float4* pos4    = (float4*)(gh + GHN + 128);              // [N]

    float* msg_agg = (float*)d_out;                           // reused as h_out
    float* pos_out = msg_agg + (size_t)NN * 64;

    prep_kernel<<<K1_GRID, 256, 0, stream>>>(h, pos, be1, We1, We2, Wc1, Wn1, Wn2,
                                             ei, wfrag, gh, a1r, a1c,
                                             msg_agg, pos_out, pos4);
    scan_kernel<<<SCAN_NB, 1024, 0, stream>>>(gh, gh + GHN);
    scat_kernel<<<SBLK, 256, 0, stream>>>(ei, gh, sorted_rc);
    bsort_kernel<<<NBUK, 256, 0, stream>>>(gh, sorted_rc);
    egnn_edge_kernel<<<ETILE, 256, 0, stream>>>(pos4, sorted_rc, a1r, a1c, We1, wfrag,
                                                be2, bc1, Wc2, bc2, msg_agg, pos_out);
    node_kernel<<<782, 256, 0, stream>>>(h, msg_agg, wfrag, bn1, bn2, msg_agg);
}